// Round 4
// baseline (140.201 us; speedup 1.0000x reference)
//
#include <hip/hip_runtime.h>
#include <stdint.h>

typedef unsigned short u16;
typedef float f32x4 __attribute__((ext_vector_type(4)));
typedef __bf16 bf16x8 __attribute__((ext_vector_type(8)));

#define AS1 __attribute__((address_space(1)))
#define AS3 __attribute__((address_space(3)))

// 1/sqrt(Dh) * log2(e), folded into w_q/b_q so softmax works in exp2 domain
#define QK_SCALE 0.18033688011112042f

__device__ __forceinline__ u16 f32_to_bf16(float f) {
    unsigned u = __float_as_uint(f);
    unsigned r = u + 0x7fffu + ((u >> 16) & 1u);
    return (u16)(r >> 16);
}

__device__ __forceinline__ float bf16_lo(unsigned u) {
    return __uint_as_float(u << 16);
}
__device__ __forceinline__ float bf16_hi(unsigned u) {
    return __uint_as_float(u & 0xffff0000u);
}

__device__ __forceinline__ void gload_lds16(const u16* g, u16* l) {
    __builtin_amdgcn_global_load_lds((const AS1 unsigned int*)g,
                                     (AS3 unsigned int*)l, 16, 0, 0);
}

// element offset into a [rows][64]-u16 tile, XOR-swizzled at 16B-chunk granularity
__device__ __forceinline__ int swz(int row, int col8) {
    return row * 64 + (((col8 ^ (row & 7)) & 7) << 3);
}
// V-transpose swizzle: spreads the dh-column write collapse (dh>>3 folded in)
__device__ __forceinline__ int swzv(int row, int col8) {
    return row * 64 + (((col8 ^ row ^ (row >> 3)) & 7) << 3);
}

// ---------------- f32 -> bf16 convert (x | w_in | w_out in one launch) -----
// Scales w_in rows < 1024 (the q-projection) by QK_SCALE.
__global__ __launch_bounds__(256) void cvt_bf16_3(const float4* __restrict__ in0,
                                                  const float4* __restrict__ in1,
                                                  const float4* __restrict__ in2,
                                                  uint2* __restrict__ out,
                                                  int n0, int n1, int ntot) {
    for (int i = blockIdx.x * blockDim.x + threadIdx.x; i < ntot;
         i += gridDim.x * blockDim.x) {
        float4 v;
        if (i < n0) v = in0[i];
        else if (i < n0 + n1) {
            v = in1[i - n0];
            if (((i - n0) >> 8) < 1024) {  // 256 float4 per 1024-elem row
                v.x *= QK_SCALE; v.y *= QK_SCALE; v.z *= QK_SCALE; v.w *= QK_SCALE;
            }
        } else v = in2[i - n0 - n1];
        uint2 o;
        o.x = (unsigned)f32_to_bf16(v.x) | ((unsigned)f32_to_bf16(v.y) << 16);
        o.y = (unsigned)f32_to_bf16(v.z) | ((unsigned)f32_to_bf16(v.w) << 16);
        out[i] = o;
    }
}

// ---------------- C[M,N] = A[M,K] * B[N,K]^T + bias ----------------
// 128x128 tile, BK=64, 4 waves (2x2). Bias cols < qcols scaled by qscale.
// Grid must be (32, gy): bm decode hardcodes gridDim.x == 32.
template <bool BF16_OUT>
__global__ __launch_bounds__(256) void gemm_bt(const u16* __restrict__ A,
                                               const u16* __restrict__ B,
                                               const float* __restrict__ bias,
                                               void* __restrict__ Cv,
                                               int M, int N, int K,
                                               int qcols, float qscale) {
    __shared__ u16 As[128 * 64];
    __shared__ u16 Bs[128 * 64];
    const int t = threadIdx.x;
    const int w = t >> 6, l = t & 63;
    const int lr = l & 15, lhi = l >> 4;
    const int wm = (w >> 1) * 64, wn = (w & 1) * 64;
    // bijective XCD swizzle (nwg % 8 == 0 for both launches)
    const int nwg = gridDim.x * gridDim.y;
    const int lin = blockIdx.y * gridDim.x + blockIdx.x;
    const int q8 = nwg >> 3;
    const int swzb = (lin & 7) * q8 + (lin >> 3);
    const int bm = swzb & 31;   // gridDim.x == 32
    const int bn = swzb >> 5;

    const u16* Ag = A + (size_t)bm * 128 * K;
    const u16* Bg = B + (size_t)bn * 128 * K;

    f32x4 acc[4][4] = {};

    for (int k0 = 0; k0 < K; k0 += 64) {
        #pragma unroll
        for (int i = 0; i < 4; ++i) {
            int c = i * 256 + t;
            int r = c >> 3, cl = c & 7;
            gload_lds16(Ag + (size_t)r * K + k0 + ((cl ^ (r & 7)) << 3), As + c * 8);
        }
        #pragma unroll
        for (int i = 0; i < 4; ++i) {
            int c = i * 256 + t;
            int r = c >> 3, cl = c & 7;
            gload_lds16(Bg + (size_t)r * K + k0 + ((cl ^ (r & 7)) << 3), Bs + c * 8);
        }
        __syncthreads();

        #pragma unroll
        for (int kks = 0; kks < 2; ++kks) {
            bf16x8 af[4], bfv[4];
            #pragma unroll
            for (int m = 0; m < 4; ++m)
                af[m] = *(const bf16x8*)(As + swz(wm + m * 16 + lr, kks * 4 + lhi));
            #pragma unroll
            for (int n = 0; n < 4; ++n)
                bfv[n] = *(const bf16x8*)(Bs + swz(wn + n * 16 + lr, kks * 4 + lhi));
            #pragma unroll
            for (int m = 0; m < 4; ++m)
                #pragma unroll
                for (int n = 0; n < 4; ++n)
                    acc[m][n] = __builtin_amdgcn_mfma_f32_16x16x32_bf16(
                        af[m], bfv[n], acc[m][n], 0, 0, 0);
        }
        __syncthreads();
    }

    const int row0 = bm * 128 + wm + lhi * 4;
    const int col0 = bn * 128 + wn + lr;
    #pragma unroll
    for (int n = 0; n < 4; ++n) {
        int col = col0 + n * 16;
        float bv = bias[col];
        if (col < qcols) bv *= qscale;
        #pragma unroll
        for (int m = 0; m < 4; ++m) {
            #pragma unroll
            for (int r = 0; r < 4; ++r) {
                int row = row0 + m * 16 + r;
                float v = acc[m][n][r] + bv;
                if constexpr (BF16_OUT)
                    ((u16*)Cv)[(size_t)row * N + col] = f32_to_bf16(v);
                else
                    ((float*)Cv)[(size_t)row * N + col] = v;
            }
        }
    }
}

// V-transpose write: thread owns rows (2g, 2g+1), cols cl*8..cl*8+7.
__device__ __forceinline__ void write_vt(u16* vt, uint4 a, uint4 b, int g, int cl) {
    unsigned aw[4] = {a.x, a.y, a.z, a.w};
    unsigned bw[4] = {b.x, b.y, b.z, b.w};
    #pragma unroll
    for (int j = 0; j < 8; ++j) {
        int dh = cl * 8 + j;
        unsigned lo = (aw[j >> 1] >> ((j & 1) * 16)) & 0xffffu;
        unsigned hi = (bw[j >> 1] >> ((j & 1) * 16)) & 0xffffu;
        *(unsigned*)(vt + swzv(dh, g >> 2) + (2 * g & 7)) = lo | (hi << 16);
    }
}

// ---------------- causal flash attention, KV-parity split ----------------
// qkv: [B*S][3072] bf16 (Q pre-scaled by QK_SCALE); partial outputs:
// p0/p1: [B*S][1024] bf16 unnormalized O per kv-parity; ml: [p][b][h][q] (m,l).
// grid: 1024 blocks x 256. Block -> (bi, parity, h, b) via XCD swizzle so all
// 32 blocks of one (b,h) share one XCD's L2 (K/V = 512 KB, L2-resident).
// Each block: passes over q-tiles {bi, 31-bi}; kv tiles t64 = par, par+2, ...
__global__ __launch_bounds__(256, 4) void attn_kernel(const u16* __restrict__ qkv,
                                                      u16* __restrict__ p0,
                                                      u16* __restrict__ p1,
                                                      float2* __restrict__ ml) {
    __shared__ u16 Ks[2][64 * 64];
    __shared__ u16 Vt[2][64 * 64];   // transposed: [dh][kv], swzv layout
    __shared__ u16 Qs[64 * 64];      // after qf load, reused as per-wave P scratch
    const int t = threadIdx.x;
    const int w = t >> 6, l = t & 63;
    const int lr = l & 15, lhi = l >> 4;
    const int orig = blockIdx.x;
    const int sid = (orig & 7) * 128 + (orig >> 3);   // XCD-chunked
    const int bh = sid >> 5, rem = sid & 31;
    const int par = rem >> 4, bi = rem & 15;
    const int h = bh & 15, b = bh >> 4;

    const u16* Kg = qkv + ((size_t)(b * 2048)) * 3072 + 1024 + h * 64;
    const u16* Vg = qkv + ((size_t)(b * 2048)) * 3072 + 2048 + h * 64;
    const int vg = t >> 3, vcl = t & 7;
    u16* pout = par ? p1 : p0;

    #pragma unroll 1
    for (int pass = 0; pass < 2; ++pass) {
        const int qt = pass ? (31 - bi) : bi;
        const u16* Qg = qkv + ((size_t)(b * 2048 + qt * 64)) * 3072 + h * 64;
        __syncthreads();
        // stage Q tile
        #pragma unroll
        for (int i = 0; i < 2; ++i) {
            int c = i * 256 + t, r = c >> 3, cl = c & 7;
            gload_lds16(Qg + (size_t)r * 3072 + ((cl ^ (r & 7)) << 3), Qs + c * 8);
        }
        const bool any = (par <= qt);
        uint4 va = {0, 0, 0, 0}, vbr = {0, 0, 0, 0};
        if (any) {  // stage first kv tile (t64 = par)
            #pragma unroll
            for (int i = 0; i < 2; ++i) {
                int c = i * 256 + t, r = c >> 3, cl = c & 7;
                gload_lds16(Kg + ((size_t)(par * 64 + r)) * 3072 + ((cl ^ (r & 7)) << 3),
                            Ks[0] + c * 8);
            }
            va = *(const uint4*)(Vg + ((size_t)(par * 64 + 2 * vg)) * 3072 + vcl * 8);
            vbr = *(const uint4*)(Vg + ((size_t)(par * 64 + 2 * vg + 1)) * 3072 + vcl * 8);
            write_vt(Vt[0], va, vbr, vg, vcl);
        }
        __syncthreads();

        bf16x8 qf[2];
        qf[0] = *(const bf16x8*)(Qs + swz(w * 16 + lr, lhi));
        qf[1] = *(const bf16x8*)(Qs + swz(w * 16 + lr, 4 + lhi));

        u16* Pw = Qs + w * 16 * 64;       // wave-private P scratch (own Q rows)
        unsigned* Pst = (unsigned*)Pw;
        f32x4 acc[4] = {};
        float m_run = -1e30f, l_run = 0.f;  // per-lane state for q-row = lr
        int cur = 0;

        for (int t64 = par; t64 <= qt; t64 += 2) {
            const bool pf = (t64 + 2 <= qt);
            if (pf) {  // prefetch parity-next tile
                #pragma unroll
                for (int i = 0; i < 2; ++i) {
                    int c = i * 256 + t, r = c >> 3, cl = c & 7;
                    gload_lds16(Kg + ((size_t)((t64 + 2) * 64 + r)) * 3072 +
                                    ((cl ^ (r & 7)) << 3),
                                Ks[cur ^ 1] + c * 8);
                }
                va = *(const uint4*)(Vg + ((size_t)((t64 + 2) * 64 + 2 * vg)) * 3072 + vcl * 8);
                vbr = *(const uint4*)(Vg + ((size_t)((t64 + 2) * 64 + 2 * vg + 1)) * 3072 + vcl * 8);
            }

            // S^T = K Q^T (Q pre-scaled): sv[n] rows kv = n*16+lhi*4+r, col q = lr
            f32x4 sv[4] = {};
            __builtin_amdgcn_s_setprio(1);
            #pragma unroll
            for (int kks = 0; kks < 2; ++kks) {
                #pragma unroll
                for (int n = 0; n < 4; ++n) {
                    bf16x8 kf = *(const bf16x8*)(Ks[cur] + swz(n * 16 + lr, kks * 4 + lhi));
                    sv[n] = __builtin_amdgcn_mfma_f32_16x16x32_bf16(kf, qf[kks], sv[n], 0, 0, 0);
                }
            }
            __builtin_amdgcn_s_setprio(0);

            const bool diag = (t64 == qt);
            float mx = -1e30f;
            if (diag) {
                #pragma unroll
                for (int n = 0; n < 4; ++n)
                    #pragma unroll
                    for (int r = 0; r < 4; ++r) {
                        float v = sv[n][r];
                        if ((n * 16 + lhi * 4 + r) > (w * 16 + lr)) v = -1e30f;
                        sv[n][r] = v;
                        mx = fmaxf(mx, v);
                    }
            } else {
                #pragma unroll
                for (int n = 0; n < 4; ++n)
                    #pragma unroll
                    for (int r = 0; r < 4; ++r)
                        mx = fmaxf(mx, sv[n][r]);
            }
            mx = fmaxf(mx, __shfl_xor(mx, 16, 64));
            mx = fmaxf(mx, __shfl_xor(mx, 32, 64));

            // defer-max (THR=8 in exp2 domain)
            if (__any(mx > m_run + 8.f)) {
                float mn = fmaxf(m_run, mx);
                float alpha = exp2f(m_run - mn);
                m_run = mn;
                l_run *= alpha;
                #pragma unroll
                for (int r = 0; r < 4; ++r) {
                    float ar = __shfl(alpha, lhi * 4 + r, 16);
                    #pragma unroll
                    for (int n = 0; n < 4; ++n) acc[n][r] *= ar;
                }
            }

            float rs = 0.f;
            #pragma unroll
            for (int n = 0; n < 4; ++n)
                #pragma unroll
                for (int r = 0; r < 4; ++r) {
                    float pe = exp2f(sv[n][r] - m_run);
                    sv[n][r] = pe;
                    rs += pe;
                }
            rs += __shfl_xor(rs, 16, 64);
            rs += __shfl_xor(rs, 32, 64);
            l_run += rs;

            // pack kv-adjacent pairs -> u32, store to wave-private A-frag scratch
            #pragma unroll
            for (int n = 0; n < 4; ++n)
                #pragma unroll
                for (int rp = 0; rp < 2; ++rp) {
                    union { unsigned u; __bf16 hh[2]; } pk;
                    pk.hh[0] = (__bf16)sv[n][2 * rp];
                    pk.hh[1] = (__bf16)sv[n][2 * rp + 1];
                    int pp = 8 * n + 2 * lhi + rp;  // kv-pair index, row q = lr
                    Pst[lr * 32 + (((pp >> 2) ^ (lr & 7)) << 2) + (pp & 3)] = pk.u;
                }

            // O += P V (wave-private P; no barrier)
            __builtin_amdgcn_s_setprio(1);
            #pragma unroll
            for (int kks = 0; kks < 2; ++kks) {
                bf16x8 pa = *(const bf16x8*)(Pw + lr * 64 +
                                             (((kks * 4 + lhi) ^ (lr & 7)) << 3));
                #pragma unroll
                for (int n = 0; n < 4; ++n) {
                    bf16x8 vb = *(const bf16x8*)(Vt[cur] + swzv(n * 16 + lr, kks * 4 + lhi));
                    acc[n] = __builtin_amdgcn_mfma_f32_16x16x32_bf16(pa, vb, acc[n], 0, 0, 0);
                }
            }
            __builtin_amdgcn_s_setprio(0);

            if (pf) write_vt(Vt[cur ^ 1], va, vbr, vg, vcl);
            __syncthreads();
            cur ^= 1;
        }

        // partial epilogue: unnormalized O (bf16) + (m, l) per q-row
        #pragma unroll
        for (int r = 0; r < 4; ++r) {
            int qg = qt * 64 + w * 16 + lhi * 4 + r;
            size_t base = ((size_t)(b * 2048 + qg)) * 1024 + h * 64;
            #pragma unroll
            for (int n = 0; n < 4; ++n)
                pout[base + n * 16 + lr] = f32_to_bf16(acc[n][r]);
        }
        if (lhi == 0)
            ml[((((size_t)par * 2 + b) * 16 + h) << 11) + qt * 64 + w * 16 + lr] =
                make_float2(m_run, l_run);
    }
}

// ---------------- combine the two kv-parity partials ----------------
// thread handles one bf16-pair; outb == p0 (in-place, own element only)
__global__ __launch_bounds__(256) void attn_combine(const unsigned* __restrict__ p0,
                                                    const unsigned* __restrict__ p1,
                                                    const float2* __restrict__ ml,
                                                    unsigned* __restrict__ outb) {
    int tg = blockIdx.x * 256 + threadIdx.x;   // [0, 4096*1024/2)
    int rowh = tg >> 5;                        // ((b*2048+q)*16+h)
    int h = rowh & 15;
    int bq = rowh >> 4;
    int b = bq >> 11, q = bq & 2047;
    size_t mi = ((((size_t)b) * 16 + h) << 11) + q;
    float2 a0 = ml[mi];
    float2 a1 = ml[mi + 65536];                // parity stride = 2*16*2048
    float m = fmaxf(a0.x, a1.x);
    float e0 = exp2f(a0.x - m), e1 = exp2f(a1.x - m);
    float inv = 1.0f / (a0.y * e0 + a1.y * e1);
    unsigned u0 = p0[tg], u1 = p1[tg];
    float r0 = (bf16_lo(u0) * e0 + bf16_lo(u1) * e1) * inv;
    float r1 = (bf16_hi(u0) * e0 + bf16_hi(u1) * e1) * inv;
    outb[tg] = (unsigned)f32_to_bf16(r0) | ((unsigned)f32_to_bf16(r1) << 16);
}

extern "C" void kernel_launch(void* const* d_in, const int* in_sizes, int n_in,
                              void* d_out, int out_size, void* d_ws, size_t ws_size,
                              hipStream_t stream) {
    const float* x = (const float*)d_in[0];
    const float* w_in = (const float*)d_in[1];
    const float* b_in = (const float*)d_in[2];
    const float* w_out = (const float*)d_in[3];
    const float* b_out = (const float*)d_in[4];
    float* out = (float*)d_out;

    // workspace layout (48 MB):
    //   xb   [4096][1024] bf16  — dead after gemm1; reused as parity-1 partial
    //   wib  [3072][1024] bf16  — dead after gemm1; reused as ml (1 MB)
    //   wob  [1024][1024] bf16  — needed by gemm2
    //   qkvb [4096][3072] bf16
    //   attnb[4096][1024] bf16  — parity-0 partial, then final attn out (in-place)
    u16* xb = (u16*)d_ws;
    u16* wib = xb + (size_t)4096 * 1024;
    u16* wob = wib + (size_t)3072 * 1024;
    u16* qkvb = wob + (size_t)1024 * 1024;
    u16* attnb = qkvb + (size_t)4096 * 3072;
    float2* ml = (float2*)wib;

    const int n0 = 4096 * 1024 / 4, n1 = 3072 * 1024 / 4, n2 = 1024 * 1024 / 4;
    cvt_bf16_3<<<2048, 256, 0, stream>>>((const float4*)x, (const float4*)w_in,
                                         (const float4*)w_out, (uint2*)xb,
                                         n0, n1, n0 + n1 + n2);

    // qkv = x @ w_in^T + b_in (q-part pre-scaled) -> bf16 [4096][3072]
    gemm_bt<true><<<dim3(32, 24), 256, 0, stream>>>(xb, wib, b_in, qkvb,
                                                    4096, 3072, 1024, 1024, QK_SCALE);
    // causal flash attention partials (kv-parity split)
    attn_kernel<<<1024, 256, 0, stream>>>(qkvb, attnb, xb, ml);
    attn_combine<<<8192, 256, 0, stream>>>((const unsigned*)attnb, (const unsigned*)xb,
                                           ml, (unsigned*)attnb);
    // out = attn @ w_out^T + b_out -> f32
    gemm_bt<false><<<dim3(32, 8), 256, 0, stream>>>(attnb, wob, b_out, out,
                                                    4096, 1024, 1024, 0, 1.0f);
}

// Round 5
// 130.309 us; speedup vs baseline: 1.0759x; 1.0759x over previous
//
#include <hip/hip_runtime.h>
#include <stdint.h>

typedef unsigned short u16;
typedef float f32x4 __attribute__((ext_vector_type(4)));
typedef __bf16 bf16x8 __attribute__((ext_vector_type(8)));

#define AS1 __attribute__((address_space(1)))
#define AS3 __attribute__((address_space(3)))

// 1/sqrt(Dh) * log2(e), folded into w_q/b_q so softmax works in exp2 domain
#define QK_SCALE 0.18033688011112042f

__device__ __forceinline__ u16 f32_to_bf16(float f) {
    unsigned u = __float_as_uint(f);
    unsigned r = u + 0x7fffu + ((u >> 16) & 1u);
    return (u16)(r >> 16);
}

__device__ __forceinline__ float bf16_f(u16 u) {
    return __uint_as_float(((unsigned)u) << 16);
}

__device__ __forceinline__ void gload_lds16(const u16* g, u16* l) {
    __builtin_amdgcn_global_load_lds((const AS1 unsigned int*)g,
                                     (AS3 unsigned int*)l, 16, 0, 0);
}

// element offset into a [rows][64]-u16 tile, XOR-swizzled at 16B-chunk granularity
__device__ __forceinline__ int swz(int row, int col8) {
    return row * 64 + (((col8 ^ (row & 7)) & 7) << 3);
}
// V-transpose swizzle: spreads the dh-column write collapse (dh>>3 folded in)
__device__ __forceinline__ int swzv(int row, int col8) {
    return row * 64 + (((col8 ^ row ^ (row >> 3)) & 7) << 3);
}

// ---------------- f32 -> bf16 convert (x | w_in | w_out in one launch) -----
__global__ __launch_bounds__(256) void cvt_bf16_3(const float4* __restrict__ in0,
                                                  const float4* __restrict__ in1,
                                                  const float4* __restrict__ in2,
                                                  uint2* __restrict__ out,
                                                  int n0, int n1, int ntot) {
    for (int i = blockIdx.x * blockDim.x + threadIdx.x; i < ntot;
         i += gridDim.x * blockDim.x) {
        float4 v;
        if (i < n0) v = in0[i];
        else if (i < n0 + n1) {
            v = in1[i - n0];
            if (((i - n0) >> 8) < 1024) {  // q-projection rows pre-scaled
                v.x *= QK_SCALE; v.y *= QK_SCALE; v.z *= QK_SCALE; v.w *= QK_SCALE;
            }
        } else v = in2[i - n0 - n1];
        uint2 o;
        o.x = (unsigned)f32_to_bf16(v.x) | ((unsigned)f32_to_bf16(v.y) << 16);
        o.y = (unsigned)f32_to_bf16(v.z) | ((unsigned)f32_to_bf16(v.w) << 16);
        out[i] = o;
    }
}

// ---------------- C[M,N] = A[M,K] * B[N,K]^T + bias ----------------
template <bool BF16_OUT>
__global__ __launch_bounds__(256) void gemm_bt(const u16* __restrict__ A,
                                               const u16* __restrict__ B,
                                               const float* __restrict__ bias,
                                               void* __restrict__ Cv,
                                               int M, int N, int K,
                                               int qcols, float qscale) {
    __shared__ u16 As[128 * 64];
    __shared__ u16 Bs[128 * 64];
    const int t = threadIdx.x;
    const int w = t >> 6, l = t & 63;
    const int lr = l & 15, lhi = l >> 4;
    const int wm = (w >> 1) * 64, wn = (w & 1) * 64;
    const int nwg = gridDim.x * gridDim.y;
    const int lin = blockIdx.y * gridDim.x + blockIdx.x;
    const int q8 = nwg >> 3;
    const int swzb = (lin & 7) * q8 + (lin >> 3);
    const int bm = swzb & 31;   // gridDim.x == 32
    const int bn = swzb >> 5;

    const u16* Ag = A + (size_t)bm * 128 * K;
    const u16* Bg = B + (size_t)bn * 128 * K;

    f32x4 acc[4][4] = {};

    for (int k0 = 0; k0 < K; k0 += 64) {
        #pragma unroll
        for (int i = 0; i < 4; ++i) {
            int c = i * 256 + t;
            int r = c >> 3, cl = c & 7;
            gload_lds16(Ag + (size_t)r * K + k0 + ((cl ^ (r & 7)) << 3), As + c * 8);
        }
        #pragma unroll
        for (int i = 0; i < 4; ++i) {
            int c = i * 256 + t;
            int r = c >> 3, cl = c & 7;
            gload_lds16(Bg + (size_t)r * K + k0 + ((cl ^ (r & 7)) << 3), Bs + c * 8);
        }
        __syncthreads();

        #pragma unroll
        for (int kks = 0; kks < 2; ++kks) {
            bf16x8 af[4], bfv[4];
            #pragma unroll
            for (int m = 0; m < 4; ++m)
                af[m] = *(const bf16x8*)(As + swz(wm + m * 16 + lr, kks * 4 + lhi));
            #pragma unroll
            for (int n = 0; n < 4; ++n)
                bfv[n] = *(const bf16x8*)(Bs + swz(wn + n * 16 + lr, kks * 4 + lhi));
            #pragma unroll
            for (int m = 0; m < 4; ++m)
                #pragma unroll
                for (int n = 0; n < 4; ++n)
                    acc[m][n] = __builtin_amdgcn_mfma_f32_16x16x32_bf16(
                        af[m], bfv[n], acc[m][n], 0, 0, 0);
        }
        __syncthreads();
    }

    const int row0 = bm * 128 + wm + lhi * 4;
    const int col0 = bn * 128 + wn + lr;
    #pragma unroll
    for (int n = 0; n < 4; ++n) {
        int col = col0 + n * 16;
        float bv = bias[col];
        if (col < qcols) bv *= qscale;
        #pragma unroll
        for (int m = 0; m < 4; ++m) {
            #pragma unroll
            for (int r = 0; r < 4; ++r) {
                int row = row0 + m * 16 + r;
                float v = acc[m][n][r] + bv;
                if constexpr (BF16_OUT)
                    ((u16*)Cv)[(size_t)row * N + col] = f32_to_bf16(v);
                else
                    ((float*)Cv)[(size_t)row * N + col] = v;
            }
        }
    }
}

// V-transpose write: thread owns rows (2g, 2g+1), cols cl*8..cl*8+7.
__device__ __forceinline__ void write_vt(u16* vt, uint4 a, uint4 b, int g, int cl) {
    unsigned aw[4] = {a.x, a.y, a.z, a.w};
    unsigned bw[4] = {b.x, b.y, b.z, b.w};
    #pragma unroll
    for (int j = 0; j < 8; ++j) {
        int dh = cl * 8 + j;
        unsigned lo = (aw[j >> 1] >> ((j & 1) * 16)) & 0xffffu;
        unsigned hi = (bw[j >> 1] >> ((j & 1) * 16)) & 0xffffu;
        *(unsigned*)(vt + swzv(dh, g >> 2) + (2 * g & 7)) = lo | (hi << 16);
    }
}

// ---------------- causal flash attention: dual-parity 8-wave blocks --------
// qkv: [B*S][3072] bf16 (Q pre-scaled); out: [B*S][1024] bf16.
// grid: 512 blocks x 512 threads. Waves 0-3: even kv tiles; 4-7: odd.
// Block bi handles q-tiles {bi, 31-bi}. Parity partials merged in LDS.
__global__ __launch_bounds__(512, 4) void attn_kernel(const u16* __restrict__ qkv,
                                                      u16* __restrict__ out) {
    __shared__ u16 Ks[2][2][64 * 64];  // [parity][dbuf], swz layout
    __shared__ u16 Vt[2][64 * 64];     // [parity], transposed [dh][kv], swzv
    __shared__ u16 Ps[8][16 * 64];     // per-wave P scratch / par1 O-tile
    const int t = threadIdx.x;
    const int w = t >> 6, l = t & 63;
    const int lr = l & 15, lhi = l >> 4;
    const int par = w >> 2, wl = w & 3;
    const int tp = t & 255;            // index within parity's 4 waves
    const int orig = blockIdx.x;
    const int sid = (orig & 7) * 64 + (orig >> 3);   // XCD-chunked
    const int bh = sid >> 4, bi = sid & 15;
    const int h = bh & 15, b = bh >> 4;

    const u16* Kg = qkv + ((size_t)(b * 2048)) * 3072 + 1024 + h * 64;
    const u16* Vg = qkv + ((size_t)(b * 2048)) * 3072 + 2048 + h * 64;
    const int vg = tp >> 3, vcl = tp & 7;
    u16* Pw = Ps[w];
    unsigned* Pst = (unsigned*)Pw;
    float2* mlX = (float2*)&Ks[0][0][0];

    #pragma unroll 1
    for (int pass = 0; pass < 2; ++pass) {
        const int qt = pass ? (31 - bi) : bi;
        __syncthreads();  // previous pass's LDS reads complete

        // Q fragments straight from global (each lane: its q-row, its k-slice)
        const u16* Qrow = qkv + ((size_t)(b * 2048 + qt * 64 + wl * 16 + lr)) * 3072 + h * 64;
        bf16x8 qf0 = *(const bf16x8*)(Qrow + lhi * 8);
        bf16x8 qf1 = *(const bf16x8*)(Qrow + 32 + lhi * 8);

        // prologue: stage kv tile t64 = par
        uint4 va = {0, 0, 0, 0}, vbr = {0, 0, 0, 0};
        if (par <= qt) {
            #pragma unroll
            for (int i = 0; i < 2; ++i) {
                int c = i * 256 + tp, r = c >> 3, cl = c & 7;
                gload_lds16(Kg + ((size_t)(par * 64 + r)) * 3072 + ((cl ^ (r & 7)) << 3),
                            &Ks[par][0][c * 8]);
            }
            va = *(const uint4*)(Vg + ((size_t)(par * 64 + 2 * vg)) * 3072 + vcl * 8);
            vbr = *(const uint4*)(Vg + ((size_t)(par * 64 + 2 * vg + 1)) * 3072 + vcl * 8);
            write_vt(Vt[par], va, vbr, vg, vcl);
        }
        __syncthreads();

        f32x4 acc[4] = {};
        float m_run = -1e30f, l_run = 0.f;  // per-lane, q-row = lr; l deferred
        int cur = 0;
        const int nt = (qt >> 1) + 1;

        for (int it = 0; it < nt; ++it) {
            const int t64 = 2 * it + par;
            const bool active = (t64 <= qt);
            const bool pfv = (t64 + 2 <= qt);
            if (pfv) {  // issue next-tile loads first (land during compute)
                #pragma unroll
                for (int i = 0; i < 2; ++i) {
                    int c = i * 256 + tp, r = c >> 3, cl = c & 7;
                    gload_lds16(Kg + ((size_t)((t64 + 2) * 64 + r)) * 3072 +
                                    ((cl ^ (r & 7)) << 3),
                                &Ks[par][cur ^ 1][c * 8]);
                }
                va = *(const uint4*)(Vg + ((size_t)((t64 + 2) * 64 + 2 * vg)) * 3072 + vcl * 8);
                vbr = *(const uint4*)(Vg + ((size_t)((t64 + 2) * 64 + 2 * vg + 1)) * 3072 + vcl * 8);
            }

            if (active) {
                // S^T = K Q^T: sv[n] rows kv = n*16+lhi*4+r, col q = lr
                f32x4 sv[4] = {};
                __builtin_amdgcn_s_setprio(1);
                #pragma unroll
                for (int kks = 0; kks < 2; ++kks) {
                    #pragma unroll
                    for (int n = 0; n < 4; ++n) {
                        bf16x8 kf = *(const bf16x8*)(&Ks[par][cur][swz(n * 16 + lr, kks * 4 + lhi)]);
                        sv[n] = __builtin_amdgcn_mfma_f32_16x16x32_bf16(
                            kf, kks ? qf1 : qf0, sv[n], 0, 0, 0);
                    }
                }
                __builtin_amdgcn_s_setprio(0);

                // causal mask (diag tile only) + tree max
                if (t64 == qt) {
                    #pragma unroll
                    for (int n = 0; n < 4; ++n)
                        #pragma unroll
                        for (int r = 0; r < 4; ++r)
                            if ((n * 16 + lhi * 4 + r) > (wl * 16 + lr)) sv[n][r] = -1e30f;
                }
                float t0 = fmaxf(fmaxf(sv[0][0], sv[0][1]), fmaxf(sv[0][2], sv[0][3]));
                float t1 = fmaxf(fmaxf(sv[1][0], sv[1][1]), fmaxf(sv[1][2], sv[1][3]));
                float t2 = fmaxf(fmaxf(sv[2][0], sv[2][1]), fmaxf(sv[2][2], sv[2][3]));
                float t3 = fmaxf(fmaxf(sv[3][0], sv[3][1]), fmaxf(sv[3][2], sv[3][3]));
                float mx = fmaxf(fmaxf(t0, t1), fmaxf(t2, t3));
                mx = fmaxf(mx, __shfl_xor(mx, 16, 64));
                mx = fmaxf(mx, __shfl_xor(mx, 32, 64));

                // defer-max (THR=8 in exp2 domain)
                if (__any(mx > m_run + 8.f)) {
                    float mn = fmaxf(m_run, mx);
                    float alpha = exp2f(m_run - mn);
                    m_run = mn;
                    l_run *= alpha;
                    #pragma unroll
                    for (int r = 0; r < 4; ++r) {
                        float ar = __shfl(alpha, lhi * 4 + r, 16);
                        #pragma unroll
                        for (int n = 0; n < 4; ++n) acc[n][r] *= ar;
                    }
                }

                // P = exp2(S - m); l kept as per-lane partial (reduced at end)
                float rs = 0.f;
                #pragma unroll
                for (int n = 0; n < 4; ++n)
                    #pragma unroll
                    for (int r = 0; r < 4; ++r) {
                        float pe = exp2f(sv[n][r] - m_run);
                        sv[n][r] = pe;
                        rs += pe;
                    }
                l_run += rs;

                // pack kv-pairs -> u32, store to wave-private A-frag scratch
                #pragma unroll
                for (int n = 0; n < 4; ++n)
                    #pragma unroll
                    for (int rp = 0; rp < 2; ++rp) {
                        union { unsigned u; __bf16 hh[2]; } pk;
                        pk.hh[0] = (__bf16)sv[n][2 * rp];
                        pk.hh[1] = (__bf16)sv[n][2 * rp + 1];
                        int pp = 8 * n + 2 * lhi + rp;
                        Pst[lr * 32 + (((pp >> 2) ^ (lr & 7)) << 2) + (pp & 3)] = pk.u;
                    }

                // O += P V  (wave-private P, single-buffered Vt[par])
                __builtin_amdgcn_s_setprio(1);
                #pragma unroll
                for (int kks = 0; kks < 2; ++kks) {
                    bf16x8 pa = *(const bf16x8*)(Pw + lr * 64 +
                                                 (((kks * 4 + lhi) ^ (lr & 7)) << 3));
                    #pragma unroll
                    for (int n = 0; n < 4; ++n) {
                        bf16x8 vb = *(const bf16x8*)(&Vt[par][swzv(n * 16 + lr, kks * 4 + lhi)]);
                        acc[n] = __builtin_amdgcn_mfma_f32_16x16x32_bf16(pa, vb, acc[n], 0, 0, 0);
                    }
                }
                __builtin_amdgcn_s_setprio(0);
            }

            __syncthreads();   // all PV reads of Vt[par] done
            if (pfv) write_vt(Vt[par], va, vbr, vg, vcl);
            __syncthreads();   // Vt ready; prefetched K drained
            cur ^= 1;
        }

        // deferred l reduction across the 4 lhi groups
        l_run += __shfl_xor(l_run, 16, 64);
        l_run += __shfl_xor(l_run, 32, 64);

        // parity exchange: par1 publishes (m,l) + unnormalized O; par0 combines
        if (par == 1) {
            if (lhi == 0) mlX[wl * 16 + lr] = make_float2(m_run, l_run);
            #pragma unroll
            for (int r = 0; r < 4; ++r)
                #pragma unroll
                for (int n = 0; n < 4; ++n)
                    Pw[(lhi * 4 + r) * 64 + n * 16 + lr] = f32_to_bf16(acc[n][r]);
        }
        __syncthreads();
        if (par == 0) {
            float2 m1l1 = mlX[wl * 16 + lr];
            float m = fmaxf(m_run, m1l1.x);
            float e0 = exp2f(m_run - m), e1 = exp2f(m1l1.x - m);
            float inv = 1.0f / (l_run * e0 + m1l1.y * e1);
            float c0 = e0 * inv, c1 = e1 * inv;
            const u16* Pq = Ps[4 + wl];
            #pragma unroll
            for (int r = 0; r < 4; ++r) {
                float c0r = __shfl(c0, lhi * 4 + r, 16);
                float c1r = __shfl(c1, lhi * 4 + r, 16);
                int qg = qt * 64 + wl * 16 + lhi * 4 + r;
                size_t base = ((size_t)(b * 2048 + qg)) * 1024 + h * 64;
                #pragma unroll
                for (int n = 0; n < 4; ++n) {
                    float v1 = bf16_f(Pq[(lhi * 4 + r) * 64 + n * 16 + lr]);
                    out[base + n * 16 + lr] = f32_to_bf16(acc[n][r] * c0r + v1 * c1r);
                }
            }
        }
    }
}

extern "C" void kernel_launch(void* const* d_in, const int* in_sizes, int n_in,
                              void* d_out, int out_size, void* d_ws, size_t ws_size,
                              hipStream_t stream) {
    const float* x = (const float*)d_in[0];
    const float* w_in = (const float*)d_in[1];
    const float* b_in = (const float*)d_in[2];
    const float* w_out = (const float*)d_in[3];
    const float* b_out = (const float*)d_in[4];
    float* out = (float*)d_out;

    // workspace layout (bf16), 48 MB
    u16* xb = (u16*)d_ws;                            // [4096][1024]
    u16* wib = xb + (size_t)4096 * 1024;             // [3072][1024]
    u16* wob = wib + (size_t)3072 * 1024;            // [1024][1024]
    u16* qkvb = wob + (size_t)1024 * 1024;           // [4096][3072]
    u16* attnb = qkvb + (size_t)4096 * 3072;         // [4096][1024]

    const int n0 = 4096 * 1024 / 4, n1 = 3072 * 1024 / 4, n2 = 1024 * 1024 / 4;
    cvt_bf16_3<<<2048, 256, 0, stream>>>((const float4*)x, (const float4*)w_in,
                                         (const float4*)w_out, (uint2*)xb,
                                         n0, n1, n0 + n1 + n2);

    // qkv = x @ w_in^T + b_in (q-part pre-scaled) -> bf16 [4096][3072]
    gemm_bt<true><<<dim3(32, 24), 256, 0, stream>>>(xb, wib, b_in, qkvb,
                                                    4096, 3072, 1024, 1024, QK_SCALE);
    // causal flash attention (dual-parity blocks, in-LDS combine)
    attn_kernel<<<512, 512, 0, stream>>>(qkvb, attnb);
    // out = attn @ w_out^T + b_out -> f32
    gemm_bt<false><<<dim3(32, 8), 256, 0, stream>>>(attnb, wob, b_out, out,
                                                    4096, 1024, 1024, 0, 1.0f);
}

// Round 6
// 118.783 us; speedup vs baseline: 1.1803x; 1.0970x over previous
//
#include <hip/hip_runtime.h>
#include <stdint.h>

typedef unsigned short u16;
typedef float f32x4 __attribute__((ext_vector_type(4)));
typedef __bf16 bf16x8 __attribute__((ext_vector_type(8)));

#define AS1 __attribute__((address_space(1)))
#define AS3 __attribute__((address_space(3)))

// 1/sqrt(Dh) * log2(e), folded into w_q/b_q so softmax works in exp2 domain
#define QK_SCALE 0.18033688011112042f

__device__ __forceinline__ u16 f32_to_bf16(float f) {
    unsigned u = __float_as_uint(f);
    unsigned r = u + 0x7fffu + ((u >> 16) & 1u);
    return (u16)(r >> 16);
}

__device__ __forceinline__ float bf16_f(u16 u) {
    return __uint_as_float(((unsigned)u) << 16);
}

__device__ __forceinline__ void gload_lds16(const u16* g, u16* l) {
    __builtin_amdgcn_global_load_lds((const AS1 unsigned int*)g,
                                     (AS3 unsigned int*)l, 16, 0, 0);
}

// element offset into a [rows][64]-u16 tile, XOR-swizzled at 16B-chunk granularity
__device__ __forceinline__ int swz(int row, int col8) {
    return row * 64 + (((col8 ^ (row & 7)) & 7) << 3);
}
// V-transpose swizzle: spreads the dh-column write collapse (dh>>3 folded in)
__device__ __forceinline__ int swzv(int row, int col8) {
    return row * 64 + (((col8 ^ row ^ (row >> 3)) & 7) << 3);
}

// ---------------- f32 -> bf16 convert (x | w_in | w_out in one launch) -----
__global__ __launch_bounds__(256) void cvt_bf16_3(const float4* __restrict__ in0,
                                                  const float4* __restrict__ in1,
                                                  const float4* __restrict__ in2,
                                                  uint2* __restrict__ out,
                                                  int n0, int n1, int ntot) {
    for (int i = blockIdx.x * blockDim.x + threadIdx.x; i < ntot;
         i += gridDim.x * blockDim.x) {
        float4 v;
        if (i < n0) v = in0[i];
        else if (i < n0 + n1) {
            v = in1[i - n0];
            if (((i - n0) >> 8) < 1024) {  // q-projection rows pre-scaled
                v.x *= QK_SCALE; v.y *= QK_SCALE; v.z *= QK_SCALE; v.w *= QK_SCALE;
            }
        } else v = in2[i - n0 - n1];
        uint2 o;
        o.x = (unsigned)f32_to_bf16(v.x) | ((unsigned)f32_to_bf16(v.y) << 16);
        o.y = (unsigned)f32_to_bf16(v.z) | ((unsigned)f32_to_bf16(v.w) << 16);
        out[i] = o;
    }
}

// ------- ring-4 deep-pipeline GEMM: C[M,N] = A[M,K] * B[N,K]^T + bias ------
// bf16 out. 256x256 tile, BK=32, 8 waves (2Mx4N), per-wave 128x64.
// LDS: 4-slot ring x (A 256x32 + B 256x32) bf16 = 128 KB dynamic.
// Schedule/phase: vmcnt(8) -> s_barrier -> stage kt+3 -> 12 ds_read_b128
//                 -> lgkmcnt(0) -> 32 MFMA.  One barrier per K-tile.
// Hazards: RAW on slot kt: vmcnt(8) leaves only kt+1,kt+2's 8 loads in flight,
//   all waves wait then barrier => slot complete. WAR on slot (kt+3)%4 =
//   (kt-1)%4: every wave's kt-1 ds_reads complete before its kt-1 MFMA waits,
//   hence before it reaches kt's barrier; stage is issued after that barrier.
__global__ __launch_bounds__(512, 2) void gemm_ring(const u16* __restrict__ A,
                                                    const u16* __restrict__ B,
                                                    const float* __restrict__ bias,
                                                    u16* __restrict__ C,
                                                    int M, int N, int K,
                                                    int qcols, float qscale) {
    extern __shared__ u16 lds[];   // A slots: [4][8192], B slots: +32768
    const int t = threadIdx.x;
    const int l = t & 63;
    const int w = t >> 6;
    const int lr = l & 15, lhi = l >> 4;
    const int wm = w >> 2, wn = w & 3;
    const int nwg = gridDim.x * gridDim.y;   // 192
    const int lin = blockIdx.y * gridDim.x + blockIdx.x;
    const int q8 = nwg >> 3;
    const int swzb = (lin & 7) * q8 + (lin >> 3);
    const int bm = swzb & 15, bn = swzb >> 4;   // gridDim.x == 16

    const u16* Ag = A + (size_t)bm * 256 * K;
    const u16* Bg = B + (size_t)bn * 256 * K;

    // staging: chunk c = i*512+t, row=c>>2, phys col-chunk=c&3,
    // global col-chunk = phys ^ ((row>>1)&3)  (inverse of the read swizzle)
    auto STAGE = [&](int kt, int slot) {
        u16* As = lds + slot * 8192;
        u16* Bs = lds + 32768 + slot * 8192;
        #pragma unroll
        for (int i = 0; i < 2; ++i) {
            int c = i * 512 + t, row = c >> 2, cp = c & 3;
            int gc = (cp ^ ((row >> 1) & 3)) << 3;
            gload_lds16(Ag + (size_t)row * K + kt * 32 + gc, As + c * 8);
            gload_lds16(Bg + (size_t)row * K + kt * 32 + gc, Bs + c * 8);
        }
    };

    f32x4 acc[8][4] = {};
    const int NT = K >> 5;          // 32
    STAGE(0, 0);
    if (NT > 1) STAGE(1, 1);
    if (NT > 2) STAGE(2, 2);

    const int ckey = (lr >> 1) & 3;  // read-side swizzle key (uniform per lane)

    for (int kt = 0; kt < NT; ++kt) {
        if (kt < NT - 2)       asm volatile("s_waitcnt vmcnt(8)" ::: "memory");
        else if (kt == NT - 2) asm volatile("s_waitcnt vmcnt(4)" ::: "memory");
        else                   asm volatile("s_waitcnt vmcnt(0)" ::: "memory");
        __builtin_amdgcn_s_barrier();

        if (kt + 3 < NT) STAGE(kt + 3, (kt + 3) & 3);

        const u16* As = lds + (kt & 3) * 8192;
        const u16* Bs = lds + 32768 + (kt & 3) * 8192;
        bf16x8 af[8], bfv[4];
        #pragma unroll
        for (int m = 0; m < 8; ++m) {
            int row = wm * 128 + m * 16 + lr;
            af[m] = *(const bf16x8*)(As + row * 32 + ((lhi ^ ckey) << 3));
        }
        #pragma unroll
        for (int n = 0; n < 4; ++n) {
            int row = wn * 64 + n * 16 + lr;
            bfv[n] = *(const bf16x8*)(Bs + row * 32 + ((lhi ^ ckey) << 3));
        }
        asm volatile("s_waitcnt lgkmcnt(0)" ::: "memory");
        __builtin_amdgcn_sched_barrier(0);
        __builtin_amdgcn_s_setprio(1);
        #pragma unroll
        for (int m = 0; m < 8; ++m)
            #pragma unroll
            for (int n = 0; n < 4; ++n)
                acc[m][n] = __builtin_amdgcn_mfma_f32_16x16x32_bf16(
                    af[m], bfv[n], acc[m][n], 0, 0, 0);
        __builtin_amdgcn_s_setprio(0);
    }

    const int row0 = bm * 256 + wm * 128 + lhi * 4;
    const int col0 = bn * 256 + wn * 64 + lr;
    #pragma unroll
    for (int n = 0; n < 4; ++n) {
        int col = col0 + n * 16;
        float bv = bias[col];
        if (col < qcols) bv *= qscale;
        #pragma unroll
        for (int m = 0; m < 8; ++m)
            #pragma unroll
            for (int r = 0; r < 4; ++r)
                C[(size_t)(row0 + m * 16 + r) * N + col] =
                    f32_to_bf16(acc[m][n][r] + bv);
    }
}

// ---------------- C[M,N] = A[M,K] * B[N,K]^T + bias (128² — gemm2) ---------
template <bool BF16_OUT>
__global__ __launch_bounds__(256) void gemm_bt(const u16* __restrict__ A,
                                               const u16* __restrict__ B,
                                               const float* __restrict__ bias,
                                               void* __restrict__ Cv,
                                               int M, int N, int K,
                                               int qcols, float qscale) {
    __shared__ u16 As[128 * 64];
    __shared__ u16 Bs[128 * 64];
    const int t = threadIdx.x;
    const int w = t >> 6, l = t & 63;
    const int lr = l & 15, lhi = l >> 4;
    const int wm = (w >> 1) * 64, wn = (w & 1) * 64;
    const int nwg = gridDim.x * gridDim.y;
    const int lin = blockIdx.y * gridDim.x + blockIdx.x;
    const int q8 = nwg >> 3;
    const int swzb = (lin & 7) * q8 + (lin >> 3);
    const int bm = swzb & 31;   // gridDim.x == 32
    const int bn = swzb >> 5;

    const u16* Ag = A + (size_t)bm * 128 * K;
    const u16* Bg = B + (size_t)bn * 128 * K;

    f32x4 acc[4][4] = {};

    for (int k0 = 0; k0 < K; k0 += 64) {
        #pragma unroll
        for (int i = 0; i < 4; ++i) {
            int c = i * 256 + t;
            int r = c >> 3, cl = c & 7;
            gload_lds16(Ag + (size_t)r * K + k0 + ((cl ^ (r & 7)) << 3), As + c * 8);
        }
        #pragma unroll
        for (int i = 0; i < 4; ++i) {
            int c = i * 256 + t;
            int r = c >> 3, cl = c & 7;
            gload_lds16(Bg + (size_t)r * K + k0 + ((cl ^ (r & 7)) << 3), Bs + c * 8);
        }
        __syncthreads();

        #pragma unroll
        for (int kks = 0; kks < 2; ++kks) {
            bf16x8 af[4], bfv[4];
            #pragma unroll
            for (int m = 0; m < 4; ++m)
                af[m] = *(const bf16x8*)(As + swz(wm + m * 16 + lr, kks * 4 + lhi));
            #pragma unroll
            for (int n = 0; n < 4; ++n)
                bfv[n] = *(const bf16x8*)(Bs + swz(wn + n * 16 + lr, kks * 4 + lhi));
            #pragma unroll
            for (int m = 0; m < 4; ++m)
                #pragma unroll
                for (int n = 0; n < 4; ++n)
                    acc[m][n] = __builtin_amdgcn_mfma_f32_16x16x32_bf16(
                        af[m], bfv[n], acc[m][n], 0, 0, 0);
        }
        __syncthreads();
    }

    const int row0 = bm * 128 + wm + lhi * 4;
    const int col0 = bn * 128 + wn + lr;
    #pragma unroll
    for (int n = 0; n < 4; ++n) {
        int col = col0 + n * 16;
        float bv = bias[col];
        if (col < qcols) bv *= qscale;
        #pragma unroll
        for (int m = 0; m < 4; ++m) {
            #pragma unroll
            for (int r = 0; r < 4; ++r) {
                int row = row0 + m * 16 + r;
                float v = acc[m][n][r] + bv;
                if constexpr (BF16_OUT)
                    ((u16*)Cv)[(size_t)row * N + col] = f32_to_bf16(v);
                else
                    ((float*)Cv)[(size_t)row * N + col] = v;
            }
        }
    }
}

// V-transpose write: thread owns rows (2g, 2g+1), cols cl*8..cl*8+7.
__device__ __forceinline__ void write_vt(u16* vt, uint4 a, uint4 b, int g, int cl) {
    unsigned aw[4] = {a.x, a.y, a.z, a.w};
    unsigned bw[4] = {b.x, b.y, b.z, b.w};
    #pragma unroll
    for (int j = 0; j < 8; ++j) {
        int dh = cl * 8 + j;
        unsigned lo = (aw[j >> 1] >> ((j & 1) * 16)) & 0xffffu;
        unsigned hi = (bw[j >> 1] >> ((j & 1) * 16)) & 0xffffu;
        *(unsigned*)(vt + swzv(dh, g >> 2) + (2 * g & 7)) = lo | (hi << 16);
    }
}

// ---------------- causal flash attention: dual-parity 8-wave blocks --------
__global__ __launch_bounds__(512, 4) void attn_kernel(const u16* __restrict__ qkv,
                                                      u16* __restrict__ out) {
    __shared__ u16 Ks[2][2][64 * 64];  // [parity][dbuf], swz layout
    __shared__ u16 Vt[2][64 * 64];     // [parity], transposed [dh][kv], swzv
    __shared__ u16 Ps[8][16 * 64];     // per-wave P scratch / par1 O-tile
    const int t = threadIdx.x;
    const int w = t >> 6, l = t & 63;
    const int lr = l & 15, lhi = l >> 4;
    const int par = w >> 2, wl = w & 3;
    const int tp = t & 255;            // index within parity's 4 waves
    const int orig = blockIdx.x;
    const int sid = (orig & 7) * 64 + (orig >> 3);   // XCD-chunked
    const int bh = sid >> 4, bi = sid & 15;
    const int h = bh & 15, b = bh >> 4;

    const u16* Kg = qkv + ((size_t)(b * 2048)) * 3072 + 1024 + h * 64;
    const u16* Vg = qkv + ((size_t)(b * 2048)) * 3072 + 2048 + h * 64;
    const int vg = tp >> 3, vcl = tp & 7;
    u16* Pw = Ps[w];
    unsigned* Pst = (unsigned*)Pw;
    float2* mlX = (float2*)&Ks[0][0][0];

    #pragma unroll 1
    for (int pass = 0; pass < 2; ++pass) {
        const int qt = pass ? (31 - bi) : bi;
        __syncthreads();  // previous pass's LDS reads complete

        const u16* Qrow = qkv + ((size_t)(b * 2048 + qt * 64 + wl * 16 + lr)) * 3072 + h * 64;
        bf16x8 qf0 = *(const bf16x8*)(Qrow + lhi * 8);
        bf16x8 qf1 = *(const bf16x8*)(Qrow + 32 + lhi * 8);

        uint4 va = {0, 0, 0, 0}, vbr = {0, 0, 0, 0};
        if (par <= qt) {
            #pragma unroll
            for (int i = 0; i < 2; ++i) {
                int c = i * 256 + tp, r = c >> 3, cl = c & 7;
                gload_lds16(Kg + ((size_t)(par * 64 + r)) * 3072 + ((cl ^ (r & 7)) << 3),
                            &Ks[par][0][c * 8]);
            }
            va = *(const uint4*)(Vg + ((size_t)(par * 64 + 2 * vg)) * 3072 + vcl * 8);
            vbr = *(const uint4*)(Vg + ((size_t)(par * 64 + 2 * vg + 1)) * 3072 + vcl * 8);
            write_vt(Vt[par], va, vbr, vg, vcl);
        }
        __syncthreads();

        f32x4 acc[4] = {};
        float m_run = -1e30f, l_run = 0.f;
        int cur = 0;
        const int nt = (qt >> 1) + 1;

        for (int it = 0; it < nt; ++it) {
            const int t64 = 2 * it + par;
            const bool active = (t64 <= qt);
            const bool pfv = (t64 + 2 <= qt);
            if (pfv) {
                #pragma unroll
                for (int i = 0; i < 2; ++i) {
                    int c = i * 256 + tp, r = c >> 3, cl = c & 7;
                    gload_lds16(Kg + ((size_t)((t64 + 2) * 64 + r)) * 3072 +
                                    ((cl ^ (r & 7)) << 3),
                                &Ks[par][cur ^ 1][c * 8]);
                }
                va = *(const uint4*)(Vg + ((size_t)((t64 + 2) * 64 + 2 * vg)) * 3072 + vcl * 8);
                vbr = *(const uint4*)(Vg + ((size_t)((t64 + 2) * 64 + 2 * vg + 1)) * 3072 + vcl * 8);
            }

            if (active) {
                f32x4 sv[4] = {};
                __builtin_amdgcn_s_setprio(1);
                #pragma unroll
                for (int kks = 0; kks < 2; ++kks) {
                    #pragma unroll
                    for (int n = 0; n < 4; ++n) {
                        bf16x8 kf = *(const bf16x8*)(&Ks[par][cur][swz(n * 16 + lr, kks * 4 + lhi)]);
                        sv[n] = __builtin_amdgcn_mfma_f32_16x16x32_bf16(
                            kf, kks ? qf1 : qf0, sv[n], 0, 0, 0);
                    }
                }
                __builtin_amdgcn_s_setprio(0);

                if (t64 == qt) {
                    #pragma unroll
                    for (int n = 0; n < 4; ++n)
                        #pragma unroll
                        for (int r = 0; r < 4; ++r)
                            if ((n * 16 + lhi * 4 + r) > (wl * 16 + lr)) sv[n][r] = -1e30f;
                }
                float t0 = fmaxf(fmaxf(sv[0][0], sv[0][1]), fmaxf(sv[0][2], sv[0][3]));
                float t1 = fmaxf(fmaxf(sv[1][0], sv[1][1]), fmaxf(sv[1][2], sv[1][3]));
                float t2 = fmaxf(fmaxf(sv[2][0], sv[2][1]), fmaxf(sv[2][2], sv[2][3]));
                float t3 = fmaxf(fmaxf(sv[3][0], sv[3][1]), fmaxf(sv[3][2], sv[3][3]));
                float mx = fmaxf(fmaxf(t0, t1), fmaxf(t2, t3));
                mx = fmaxf(mx, __shfl_xor(mx, 16, 64));
                mx = fmaxf(mx, __shfl_xor(mx, 32, 64));

                if (__any(mx > m_run + 8.f)) {
                    float mn = fmaxf(m_run, mx);
                    float alpha = exp2f(m_run - mn);
                    m_run = mn;
                    l_run *= alpha;
                    #pragma unroll
                    for (int r = 0; r < 4; ++r) {
                        float ar = __shfl(alpha, lhi * 4 + r, 16);
                        #pragma unroll
                        for (int n = 0; n < 4; ++n) acc[n][r] *= ar;
                    }
                }

                float rs = 0.f;
                #pragma unroll
                for (int n = 0; n < 4; ++n)
                    #pragma unroll
                    for (int r = 0; r < 4; ++r) {
                        float pe = exp2f(sv[n][r] - m_run);
                        sv[n][r] = pe;
                        rs += pe;
                    }
                l_run += rs;

                #pragma unroll
                for (int n = 0; n < 4; ++n)
                    #pragma unroll
                    for (int rp = 0; rp < 2; ++rp) {
                        union { unsigned u; __bf16 hh[2]; } pk;
                        pk.hh[0] = (__bf16)sv[n][2 * rp];
                        pk.hh[1] = (__bf16)sv[n][2 * rp + 1];
                        int pp = 8 * n + 2 * lhi + rp;
                        Pst[lr * 32 + (((pp >> 2) ^ (lr & 7)) << 2) + (pp & 3)] = pk.u;
                    }

                __builtin_amdgcn_s_setprio(1);
                #pragma unroll
                for (int kks = 0; kks < 2; ++kks) {
                    bf16x8 pa = *(const bf16x8*)(Pw + lr * 64 +
                                                 (((kks * 4 + lhi) ^ (lr & 7)) << 3));
                    #pragma unroll
                    for (int n = 0; n < 4; ++n) {
                        bf16x8 vb = *(const bf16x8*)(&Vt[par][swzv(n * 16 + lr, kks * 4 + lhi)]);
                        acc[n] = __builtin_amdgcn_mfma_f32_16x16x32_bf16(pa, vb, acc[n], 0, 0, 0);
                    }
                }
                __builtin_amdgcn_s_setprio(0);
            }

            __syncthreads();   // all PV reads of Vt[par] done
            if (pfv) write_vt(Vt[par], va, vbr, vg, vcl);
            __syncthreads();   // Vt ready; prefetched K drained
            cur ^= 1;
        }

        l_run += __shfl_xor(l_run, 16, 64);
        l_run += __shfl_xor(l_run, 32, 64);

        if (par == 1) {
            if (lhi == 0) mlX[wl * 16 + lr] = make_float2(m_run, l_run);
            #pragma unroll
            for (int r = 0; r < 4; ++r)
                #pragma unroll
                for (int n = 0; n < 4; ++n)
                    Pw[(lhi * 4 + r) * 64 + n * 16 + lr] = f32_to_bf16(acc[n][r]);
        }
        __syncthreads();
        if (par == 0) {
            float2 m1l1 = mlX[wl * 16 + lr];
            float m = fmaxf(m_run, m1l1.x);
            float e0 = exp2f(m_run - m), e1 = exp2f(m1l1.x - m);
            float inv = 1.0f / (l_run * e0 + m1l1.y * e1);
            float c0 = e0 * inv, c1 = e1 * inv;
            const u16* Pq = Ps[4 + wl];
            #pragma unroll
            for (int r = 0; r < 4; ++r) {
                float c0r = __shfl(c0, lhi * 4 + r, 16);
                float c1r = __shfl(c1, lhi * 4 + r, 16);
                int qg = qt * 64 + wl * 16 + lhi * 4 + r;
                size_t base = ((size_t)(b * 2048 + qg)) * 1024 + h * 64;
                #pragma unroll
                for (int n = 0; n < 4; ++n) {
                    float v1 = bf16_f(Pq[(lhi * 4 + r) * 64 + n * 16 + lr]);
                    out[base + n * 16 + lr] = f32_to_bf16(acc[n][r] * c0r + v1 * c1r);
                }
            }
        }
    }
}

extern "C" void kernel_launch(void* const* d_in, const int* in_sizes, int n_in,
                              void* d_out, int out_size, void* d_ws, size_t ws_size,
                              hipStream_t stream) {
    const float* x = (const float*)d_in[0];
    const float* w_in = (const float*)d_in[1];
    const float* b_in = (const float*)d_in[2];
    const float* w_out = (const float*)d_in[3];
    const float* b_out = (const float*)d_in[4];
    float* out = (float*)d_out;

    // workspace layout (bf16), 48 MB
    u16* xb = (u16*)d_ws;                            // [4096][1024]
    u16* wib = xb + (size_t)4096 * 1024;             // [3072][1024]
    u16* wob = wib + (size_t)3072 * 1024;            // [1024][1024]
    u16* qkvb = wob + (size_t)1024 * 1024;           // [4096][3072]
    u16* attnb = qkvb + (size_t)4096 * 3072;         // [4096][1024]

    const int n0 = 4096 * 1024 / 4, n1 = 3072 * 1024 / 4, n2 = 1024 * 1024 / 4;
    cvt_bf16_3<<<2048, 256, 0, stream>>>((const float4*)x, (const float4*)w_in,
                                         (const float4*)w_out, (uint2*)xb,
                                         n0, n1, n0 + n1 + n2);

    // qkv = x @ w_in^T + b_in (q-part pre-scaled) -> bf16 [4096][3072]
    (void)hipFuncSetAttribute((const void*)gemm_ring,
                              hipFuncAttributeMaxDynamicSharedMemorySize, 131072);
    gemm_ring<<<dim3(16, 12), 512, 131072, stream>>>(xb, wib, b_in, qkvb,
                                                     4096, 3072, 1024, 1024, QK_SCALE);
    // causal flash attention (dual-parity blocks, in-LDS combine)
    attn_kernel<<<512, 512, 0, stream>>>(qkvb, attnb);
    // out = attn @ w_out^T + b_out -> f32
    gemm_bt<false><<<dim3(32, 8), 256, 0, stream>>>(attnb, wob, b_out, out,
                                                    4096, 1024, 1024, 0, 1.0f);
}

// Round 7
// 109.335 us; speedup vs baseline: 1.2823x; 1.0864x over previous
//
#include <hip/hip_runtime.h>
#include <stdint.h>

typedef unsigned short u16;
typedef float f32x4 __attribute__((ext_vector_type(4)));
typedef __bf16 bf16x8 __attribute__((ext_vector_type(8)));

#define AS1 __attribute__((address_space(1)))
#define AS3 __attribute__((address_space(3)))

// 1/sqrt(Dh) * log2(e), folded into w_q/b_q so softmax works in exp2 domain
#define QK_SCALE 0.18033688011112042f

__device__ __forceinline__ u16 f32_to_bf16(float f) {
    unsigned u = __float_as_uint(f);
    unsigned r = u + 0x7fffu + ((u >> 16) & 1u);
    return (u16)(r >> 16);
}

__device__ __forceinline__ float bf16_f(u16 u) {
    return __uint_as_float(((unsigned)u) << 16);
}

__device__ __forceinline__ void gload_lds16(const u16* g, u16* l) {
    __builtin_amdgcn_global_load_lds((const AS1 unsigned int*)g,
                                     (AS3 unsigned int*)l, 16, 0, 0);
}

// element offset into a [rows][64]-u16 tile, XOR-swizzled at 16B-chunk granularity
__device__ __forceinline__ int swz(int row, int col8) {
    return row * 64 + (((col8 ^ (row & 7)) & 7) << 3);
}
// V-transpose swizzle: spreads the dh-column write collapse (dh>>3 folded in)
__device__ __forceinline__ int swzv(int row, int col8) {
    return row * 64 + (((col8 ^ row ^ (row >> 3)) & 7) << 3);
}

// ---------------- f32 -> bf16 convert (x | w_in | w_out in one launch) -----
__global__ __launch_bounds__(256) void cvt_bf16_3(const float4* __restrict__ in0,
                                                  const float4* __restrict__ in1,
                                                  const float4* __restrict__ in2,
                                                  uint2* __restrict__ out,
                                                  int n0, int n1, int ntot) {
    for (int i = blockIdx.x * blockDim.x + threadIdx.x; i < ntot;
         i += gridDim.x * blockDim.x) {
        float4 v;
        if (i < n0) v = in0[i];
        else if (i < n0 + n1) {
            v = in1[i - n0];
            if (((i - n0) >> 8) < 1024) {  // q-projection rows pre-scaled
                v.x *= QK_SCALE; v.y *= QK_SCALE; v.z *= QK_SCALE; v.w *= QK_SCALE;
            }
        } else v = in2[i - n0 - n1];
        uint2 o;
        o.x = (unsigned)f32_to_bf16(v.x) | ((unsigned)f32_to_bf16(v.y) << 16);
        o.y = (unsigned)f32_to_bf16(v.z) | ((unsigned)f32_to_bf16(v.w) << 16);
        out[i] = o;
    }
}

// ------- ring-4 deep-pipeline GEMM: C[M,N] = A[M,K] * B[N,K]^T + bias ------
// BM=128, BN=BNT (384 or 128), BK=32, 8 waves (2Mx4N), per-wave 64 x BNT/4.
// LDS ring of 4 slots: A[128][32] + B[BNT][32] bf16 per slot.
// Grid MUST be (32, N/BNT) with N/BNT == 8 (XCD swizzle: one bn per XCD).
// Schedule/phase: vmcnt(2*NCH) -> s_barrier -> stage kt+3 -> ds_reads
//                 -> lgkmcnt(0) -> MFMA cluster.  One barrier per K-tile.
// Hazards (ring-4): RAW slot kt: vmcnt leaves only kt+1,kt+2 in flight ->
//   barrier => slot kt complete.  WAR slot (kt+3)&3 = (kt-1)&3: every wave's
//   kt-1 ds_reads completed (lgkmcnt(0) before its MFMA) before it reached
//   barrier(kt); stage is issued after that barrier.
template <int BNT, bool BF16_OUT>
__global__ __launch_bounds__(512, 2) void gemm_ring(const u16* __restrict__ A,
                                                    const u16* __restrict__ B,
                                                    const float* __restrict__ bias,
                                                    void* __restrict__ Cv,
                                                    int M, int N, int K,
                                                    int qcols, float qscale) {
    extern __shared__ u16 lds[];
    constexpr int NACC = BNT / 64;          // col blocks per wave (6 or 2)
    constexpr int NCH = (128 + BNT) >> 7;   // staging chunks per thread (4 or 2)
    constexpr int ASZ = 128 * 32;           // elems per A slot
    constexpr int BSZ = BNT * 32;           // elems per B slot
    const int t = threadIdx.x;
    const int l = t & 63, w = t >> 6;
    const int lr = l & 15, lhi = l >> 4;
    const int wm = w >> 2, wn = w & 3;
    // XCD-chunked swizzle: XCD x gets sid [32x,32x+32) -> one bn (B panel) per XCD
    const int orig = blockIdx.y * gridDim.x + blockIdx.x;   // nwg == 256
    const int sid = (orig & 7) * 32 + (orig >> 3);
    const int bm = sid & 31, bn = sid >> 5;

    const u16* Ag = A + (size_t)bm * 128 * K;
    const u16* Bg = B + (size_t)bn * BNT * K;

    // stage: chunk c -> row=c>>2, phys col-chunk=c&3; global col-chunk is the
    // inverse swizzle (cp ^ bits1..2 of row) so swizzled reads see linear cols.
    auto STAGE = [&](int kt, int slot) {
        u16* As = lds + slot * ASZ;
        u16* Bs = lds + 4 * ASZ + slot * BSZ;
        {
            int c = t, row = c >> 2, cp = c & 3;
            int gc = (cp ^ ((row >> 1) & 3)) << 3;
            gload_lds16(Ag + (size_t)row * K + kt * 32 + gc, As + c * 8);
        }
        #pragma unroll
        for (int i = 0; i < NCH - 1; ++i) {
            int c = i * 512 + t, row = c >> 2, cp = c & 3;
            int gc = (cp ^ ((row >> 1) & 3)) << 3;
            gload_lds16(Bg + (size_t)row * K + kt * 32 + gc, Bs + c * 8);
        }
    };

    f32x4 acc[4][NACC] = {};
    const int NT = K >> 5;          // 32
    STAGE(0, 0);
    STAGE(1, 1);
    STAGE(2, 2);

    const int ckey = (lr >> 1) & 3;  // read-side swizzle key

    for (int kt = 0; kt < NT; ++kt) {
        if (kt < NT - 2) {
            if constexpr (NCH == 4) asm volatile("s_waitcnt vmcnt(8)" ::: "memory");
            else                    asm volatile("s_waitcnt vmcnt(4)" ::: "memory");
        } else if (kt == NT - 2) {
            if constexpr (NCH == 4) asm volatile("s_waitcnt vmcnt(4)" ::: "memory");
            else                    asm volatile("s_waitcnt vmcnt(2)" ::: "memory");
        } else {
            asm volatile("s_waitcnt vmcnt(0)" ::: "memory");
        }
        __builtin_amdgcn_s_barrier();

        if (kt + 3 < NT) STAGE(kt + 3, (kt + 3) & 3);

        const u16* As = lds + (kt & 3) * ASZ;
        const u16* Bs = lds + 4 * ASZ + (kt & 3) * BSZ;
        bf16x8 af[4], bfv[NACC];
        #pragma unroll
        for (int m = 0; m < 4; ++m) {
            int row = wm * 64 + m * 16 + lr;
            af[m] = *(const bf16x8*)(As + row * 32 + ((lhi ^ ckey) << 3));
        }
        #pragma unroll
        for (int n = 0; n < NACC; ++n) {
            int row = wn * (BNT / 4) + n * 16 + lr;
            bfv[n] = *(const bf16x8*)(Bs + row * 32 + ((lhi ^ ckey) << 3));
        }
        asm volatile("s_waitcnt lgkmcnt(0)" ::: "memory");
        __builtin_amdgcn_sched_barrier(0);
        __builtin_amdgcn_s_setprio(1);
        #pragma unroll
        for (int m = 0; m < 4; ++m)
            #pragma unroll
            for (int n = 0; n < NACC; ++n)
                acc[m][n] = __builtin_amdgcn_mfma_f32_16x16x32_bf16(
                    af[m], bfv[n], acc[m][n], 0, 0, 0);
        __builtin_amdgcn_s_setprio(0);
    }

    const int row0 = bm * 128 + wm * 64 + lhi * 4;
    const int col0 = bn * BNT + wn * (BNT / 4) + lr;
    #pragma unroll
    for (int n = 0; n < NACC; ++n) {
        int col = col0 + n * 16;
        float bv = bias[col];
        if (col < qcols) bv *= qscale;
        #pragma unroll
        for (int m = 0; m < 4; ++m)
            #pragma unroll
            for (int r = 0; r < 4; ++r) {
                int row = row0 + m * 16 + r;
                float v = acc[m][n][r] + bv;
                if constexpr (BF16_OUT)
                    ((u16*)Cv)[(size_t)row * N + col] = f32_to_bf16(v);
                else
                    ((float*)Cv)[(size_t)row * N + col] = v;
            }
    }
}

// V-transpose write: thread owns rows (2g, 2g+1), cols cl*8..cl*8+7.
// v_perm packs (lo16 of a-word, lo/hi16 of b-word) in one op per output.
__device__ __forceinline__ void write_vt(u16* vt, uint4 a, uint4 b, int g, int cl) {
    unsigned aw[4] = {a.x, a.y, a.z, a.w};
    unsigned bw[4] = {b.x, b.y, b.z, b.w};
    #pragma unroll
    for (int j = 0; j < 8; ++j) {
        int dh = cl * 8 + j;
        unsigned sel = (j & 1) ? 0x07060302u : 0x05040100u;
        unsigned v = __builtin_amdgcn_perm(bw[j >> 1], aw[j >> 1], sel);
        *(unsigned*)(vt + swzv(dh, g >> 2) + (2 * g & 7)) = v;
    }
}

// ---------------- causal flash attention: dual-parity 8-wave blocks --------
// Dynamic LDS 80 KB: Ks[2][2][4096] | Vt[2][2][4096] | Ps[8][1024].
// One barrier per KV iter (K and V both double-buffered).
__global__ __launch_bounds__(512, 4) void attn_kernel(const u16* __restrict__ qkv,
                                                      u16* __restrict__ out) {
    extern __shared__ u16 alds[];
    const int t = threadIdx.x;
    const int w = t >> 6, l = t & 63;
    const int lr = l & 15, lhi = l >> 4;
    const int par = w >> 2, wl = w & 3;
    const int tp = t & 255;            // index within parity's 4 waves
    const int orig = blockIdx.x;
    const int sid = (orig & 7) * 64 + (orig >> 3);   // XCD-chunked
    const int bh = sid >> 4, bi = sid & 15;
    const int h = bh & 15, b = bh >> 4;

    const u16* Kg = qkv + ((size_t)(b * 2048)) * 3072 + 1024 + h * 64;
    const u16* Vg = qkv + ((size_t)(b * 2048)) * 3072 + 2048 + h * 64;
    const int vg = tp >> 3, vcl = tp & 7;
    u16* KsP = alds + par * 8192;           // [2][4096] dbuf
    u16* VtP = alds + 16384 + par * 8192;   // [2][4096] dbuf
    u16* Pw = alds + 32768 + w * 1024;
    unsigned* Pst = (unsigned*)Pw;
    float2* mlX = (float2*)alds;            // aliases Ks[0][0]; epilogue-only

    #pragma unroll 1
    for (int pass = 0; pass < 2; ++pass) {
        const int qt = pass ? (31 - bi) : bi;
        __syncthreads();  // previous pass's LDS fully consumed

        const u16* Qrow = qkv + ((size_t)(b * 2048 + qt * 64 + wl * 16 + lr)) * 3072 + h * 64;
        bf16x8 qf0 = *(const bf16x8*)(Qrow + lhi * 8);
        bf16x8 qf1 = *(const bf16x8*)(Qrow + 32 + lhi * 8);

        uint4 va = {0, 0, 0, 0}, vbr = {0, 0, 0, 0};
        if (par <= qt) {  // prologue: stage kv tile t64 = par into buf 0
            #pragma unroll
            for (int i = 0; i < 2; ++i) {
                int c = i * 256 + tp, r = c >> 3, cl = c & 7;
                gload_lds16(Kg + ((size_t)(par * 64 + r)) * 3072 + ((cl ^ (r & 7)) << 3),
                            KsP + c * 8);
            }
            va = *(const uint4*)(Vg + ((size_t)(par * 64 + 2 * vg)) * 3072 + vcl * 8);
            vbr = *(const uint4*)(Vg + ((size_t)(par * 64 + 2 * vg + 1)) * 3072 + vcl * 8);
            write_vt(VtP, va, vbr, vg, vcl);
        }
        __syncthreads();

        f32x4 acc[4] = {};
        float m_run = -1e30f, l_run = 0.f;  // per-lane, q-row = lr; l deferred
        int cur = 0;
        const int nt = (qt >> 1) + 1;

        for (int it = 0; it < nt; ++it) {
            const int t64 = 2 * it + par;
            const bool active = (t64 <= qt);
            const bool pf = (t64 + 2 <= qt);
            if (pf) {  // issue next-tile loads first — land during compute
                #pragma unroll
                for (int i = 0; i < 2; ++i) {
                    int c = i * 256 + tp, r = c >> 3, cl = c & 7;
                    gload_lds16(Kg + ((size_t)((t64 + 2) * 64 + r)) * 3072 +
                                    ((cl ^ (r & 7)) << 3),
                                KsP + (cur ^ 1) * 4096 + c * 8);
                }
                va = *(const uint4*)(Vg + ((size_t)((t64 + 2) * 64 + 2 * vg)) * 3072 + vcl * 8);
                vbr = *(const uint4*)(Vg + ((size_t)((t64 + 2) * 64 + 2 * vg + 1)) * 3072 + vcl * 8);
            }

            f32x4 sv[4] = {};
            if (active) {
                // S^T = K Q^T: sv[n] rows kv = n*16+lhi*4+r, col q = lr
                const u16* Kc = KsP + cur * 4096;
                __builtin_amdgcn_s_setprio(1);
                #pragma unroll
                for (int kks = 0; kks < 2; ++kks) {
                    #pragma unroll
                    for (int n = 0; n < 4; ++n) {
                        bf16x8 kf = *(const bf16x8*)(Kc + swz(n * 16 + lr, kks * 4 + lhi));
                        sv[n] = __builtin_amdgcn_mfma_f32_16x16x32_bf16(
                            kf, kks ? qf1 : qf0, sv[n], 0, 0, 0);
                    }
                }
                __builtin_amdgcn_s_setprio(0);

                if (t64 == qt) {  // causal mask (diag tile only)
                    #pragma unroll
                    for (int n = 0; n < 4; ++n)
                        #pragma unroll
                        for (int r = 0; r < 4; ++r)
                            if ((n * 16 + lhi * 4 + r) > (wl * 16 + lr)) sv[n][r] = -1e30f;
                }
                float t0 = fmaxf(fmaxf(sv[0][0], sv[0][1]), fmaxf(sv[0][2], sv[0][3]));
                float t1 = fmaxf(fmaxf(sv[1][0], sv[1][1]), fmaxf(sv[1][2], sv[1][3]));
                float t2 = fmaxf(fmaxf(sv[2][0], sv[2][1]), fmaxf(sv[2][2], sv[2][3]));
                float t3 = fmaxf(fmaxf(sv[3][0], sv[3][1]), fmaxf(sv[3][2], sv[3][3]));
                float mx = fmaxf(fmaxf(t0, t1), fmaxf(t2, t3));
                mx = fmaxf(mx, __shfl_xor(mx, 16, 64));
                mx = fmaxf(mx, __shfl_xor(mx, 32, 64));

                if (__any(mx > m_run + 8.f)) {  // defer-max (THR=8, exp2 domain)
                    float mn = fmaxf(m_run, mx);
                    float alpha = exp2f(m_run - mn);
                    m_run = mn;
                    l_run *= alpha;
                    #pragma unroll
                    for (int r = 0; r < 4; ++r) {
                        float ar = __shfl(alpha, lhi * 4 + r, 16);
                        #pragma unroll
                        for (int n = 0; n < 4; ++n) acc[n][r] *= ar;
                    }
                }

                float rs = 0.f;
                #pragma unroll
                for (int n = 0; n < 4; ++n)
                    #pragma unroll
                    for (int r = 0; r < 4; ++r) {
                        float pe = exp2f(sv[n][r] - m_run);
                        sv[n][r] = pe;
                        rs += pe;
                    }
                l_run += rs;

                // pack kv-pairs -> u32, store to wave-private A-frag scratch
                #pragma unroll
                for (int n = 0; n < 4; ++n)
                    #pragma unroll
                    for (int rp = 0; rp < 2; ++rp) {
                        union { unsigned u; __bf16 hh[2]; } pk;
                        pk.hh[0] = (__bf16)sv[n][2 * rp];
                        pk.hh[1] = (__bf16)sv[n][2 * rp + 1];
                        int pp = 8 * n + 2 * lhi + rp;
                        Pst[lr * 32 + (((pp >> 2) ^ (lr & 7)) << 2) + (pp & 3)] = pk.u;
                    }
            }

            // V(t+2) -> other Vt buffer (waits only on va/vbr; overlapped above)
            if (pf) write_vt(VtP + (cur ^ 1) * 4096, va, vbr, vg, vcl);

            if (active) {
                // O += P V  (wave-private P; Vt[cur])
                const u16* Vc = VtP + cur * 4096;
                __builtin_amdgcn_s_setprio(1);
                #pragma unroll
                for (int kks = 0; kks < 2; ++kks) {
                    bf16x8 pa = *(const bf16x8*)(Pw + lr * 64 +
                                                 (((kks * 4 + lhi) ^ (lr & 7)) << 3));
                    #pragma unroll
                    for (int n = 0; n < 4; ++n) {
                        bf16x8 vb = *(const bf16x8*)(Vc + swzv(n * 16 + lr, kks * 4 + lhi));
                        acc[n] = __builtin_amdgcn_mfma_f32_16x16x32_bf16(pa, vb, acc[n], 0, 0, 0);
                    }
                }
                __builtin_amdgcn_s_setprio(0);
            }

            __syncthreads();   // staged K drained; Vt/Ks buffers flip
            cur ^= 1;
        }

        // deferred l reduction across the 4 lhi groups
        l_run += __shfl_xor(l_run, 16, 64);
        l_run += __shfl_xor(l_run, 32, 64);

        // parity exchange: par1 publishes (m,l) + unnormalized O; par0 combines
        if (par == 1) {
            if (lhi == 0) mlX[wl * 16 + lr] = make_float2(m_run, l_run);
            #pragma unroll
            for (int r = 0; r < 4; ++r)
                #pragma unroll
                for (int n = 0; n < 4; ++n)
                    Pw[(lhi * 4 + r) * 64 + n * 16 + lr] = f32_to_bf16(acc[n][r]);
        }
        __syncthreads();
        if (par == 0) {
            float2 m1l1 = mlX[wl * 16 + lr];
            float m = fmaxf(m_run, m1l1.x);
            float e0 = exp2f(m_run - m), e1 = exp2f(m1l1.x - m);
            float inv = 1.0f / (l_run * e0 + m1l1.y * e1);
            float c0 = e0 * inv, c1 = e1 * inv;
            const u16* Pq = alds + 32768 + (4 + wl) * 1024;
            #pragma unroll
            for (int r = 0; r < 4; ++r) {
                float c0r = __shfl(c0, lhi * 4 + r, 16);
                float c1r = __shfl(c1, lhi * 4 + r, 16);
                int qg = qt * 64 + wl * 16 + lhi * 4 + r;
                size_t base = ((size_t)(b * 2048 + qg)) * 1024 + h * 64;
                #pragma unroll
                for (int n = 0; n < 4; ++n) {
                    float v1 = bf16_f(Pq[(lhi * 4 + r) * 64 + n * 16 + lr]);
                    out[base + n * 16 + lr] = f32_to_bf16(acc[n][r] * c0r + v1 * c1r);
                }
            }
        }
    }
}

extern "C" void kernel_launch(void* const* d_in, const int* in_sizes, int n_in,
                              void* d_out, int out_size, void* d_ws, size_t ws_size,
                              hipStream_t stream) {
    const float* x = (const float*)d_in[0];
    const float* w_in = (const float*)d_in[1];
    const float* b_in = (const float*)d_in[2];
    const float* w_out = (const float*)d_in[3];
    const float* b_out = (const float*)d_in[4];
    float* out = (float*)d_out;

    // workspace layout (bf16), 48 MB
    u16* xb = (u16*)d_ws;                            // [4096][1024]
    u16* wib = xb + (size_t)4096 * 1024;             // [3072][1024]
    u16* wob = wib + (size_t)3072 * 1024;            // [1024][1024]
    u16* qkvb = wob + (size_t)1024 * 1024;           // [4096][3072]
    u16* attnb = qkvb + (size_t)4096 * 3072;         // [4096][1024]

    const int n0 = 4096 * 1024 / 4, n1 = 3072 * 1024 / 4, n2 = 1024 * 1024 / 4;
    cvt_bf16_3<<<2048, 256, 0, stream>>>((const float4*)x, (const float4*)w_in,
                                         (const float4*)w_out, (uint2*)xb,
                                         n0, n1, n0 + n1 + n2);

    (void)hipFuncSetAttribute((const void*)gemm_ring<384, true>,
                              hipFuncAttributeMaxDynamicSharedMemorySize, 131072);
    (void)hipFuncSetAttribute((const void*)gemm_ring<128, false>,
                              hipFuncAttributeMaxDynamicSharedMemorySize, 65536);
    (void)hipFuncSetAttribute((const void*)attn_kernel,
                              hipFuncAttributeMaxDynamicSharedMemorySize, 81920);

    // qkv = x @ w_in^T + b_in (q-part pre-scaled) -> bf16 [4096][3072]
    gemm_ring<384, true><<<dim3(32, 8), 512, 131072, stream>>>(
        xb, wib, b_in, qkvb, 4096, 3072, 1024, 1024, QK_SCALE);
    // causal flash attention (dual-parity blocks, in-LDS combine)
    attn_kernel<<<512, 512, 81920, stream>>>(qkvb, attnb);
    // out = attn @ w_out^T + b_out -> f32
    gemm_ring<128, false><<<dim3(32, 8), 512, 65536, stream>>>(
        attnb, wob, b_out, out, 4096, 1024, 1024, 0, 1.0f);
}

// Round 8
// 107.434 us; speedup vs baseline: 1.3050x; 1.0177x over previous
//
#include <hip/hip_runtime.h>
#include <stdint.h>

typedef unsigned short u16;
typedef float f32x4 __attribute__((ext_vector_type(4)));
typedef __bf16 bf16x8 __attribute__((ext_vector_type(8)));

#define AS1 __attribute__((address_space(1)))
#define AS3 __attribute__((address_space(3)))

// 1/sqrt(Dh) * log2(e), folded into w_q/b_q so softmax works in exp2 domain
#define QK_SCALE 0.18033688011112042f

__device__ __forceinline__ u16 f32_to_bf16(float f) {
    unsigned u = __float_as_uint(f);
    unsigned r = u + 0x7fffu + ((u >> 16) & 1u);
    return (u16)(r >> 16);
}

__device__ __forceinline__ float bf16_f(u16 u) {
    return __uint_as_float(((unsigned)u) << 16);
}

__device__ __forceinline__ void gload_lds16(const u16* g, u16* l) {
    __builtin_amdgcn_global_load_lds((const AS1 unsigned int*)g,
                                     (AS3 unsigned int*)l, 16, 0, 0);
}

// element offset into a [rows][64]-u16 tile, XOR-swizzled at 16B-chunk granularity
__device__ __forceinline__ int swz(int row, int col8) {
    return row * 64 + (((col8 ^ (row & 7)) & 7) << 3);
}
// V-transpose swizzle: spreads the dh-column write collapse (dh>>3 folded in)
__device__ __forceinline__ int swzv(int row, int col8) {
    return row * 64 + (((col8 ^ row ^ (row >> 3)) & 7) << 3);
}

// ---------------- f32 -> bf16 convert (x | w_in | w_out in one launch) -----
__global__ __launch_bounds__(256) void cvt_bf16_3(const float4* __restrict__ in0,
                                                  const float4* __restrict__ in1,
                                                  const float4* __restrict__ in2,
                                                  uint2* __restrict__ out,
                                                  int n0, int n1, int ntot) {
    for (int i = blockIdx.x * blockDim.x + threadIdx.x; i < ntot;
         i += gridDim.x * blockDim.x) {
        float4 v;
        if (i < n0) v = in0[i];
        else if (i < n0 + n1) {
            v = in1[i - n0];
            if (((i - n0) >> 8) < 1024) {  // q-projection rows pre-scaled
                v.x *= QK_SCALE; v.y *= QK_SCALE; v.z *= QK_SCALE; v.w *= QK_SCALE;
            }
        } else v = in2[i - n0 - n1];
        uint2 o;
        o.x = (unsigned)f32_to_bf16(v.x) | ((unsigned)f32_to_bf16(v.y) << 16);
        o.y = (unsigned)f32_to_bf16(v.z) | ((unsigned)f32_to_bf16(v.w) << 16);
        out[i] = o;
    }
}

// ------- ring-4 deep-pipeline GEMM: C[M,N] = A[M,K] * B[N,K]^T + bias ------
// BM=128, BN=BNT (384 or 128), BK=32, 8 waves (2Mx4N), per-wave 64 x BNT/4.
// Schedule/phase: vmcnt(2*NCH) -> s_barrier -> stage kt+3 -> ds_reads
//                 -> lgkmcnt(0) -> MFMA cluster.  One barrier per K-tile.
template <int BNT, bool BF16_OUT>
__global__ __launch_bounds__(512, 2) void gemm_ring(const u16* __restrict__ A,
                                                    const u16* __restrict__ B,
                                                    const float* __restrict__ bias,
                                                    void* __restrict__ Cv,
                                                    int M, int N, int K,
                                                    int qcols, float qscale) {
    extern __shared__ u16 lds[];
    constexpr int NACC = BNT / 64;          // col blocks per wave (6 or 2)
    constexpr int NCH = (128 + BNT) >> 7;   // staging chunks per thread (4 or 2)
    constexpr int ASZ = 128 * 32;           // elems per A slot
    constexpr int BSZ = BNT * 32;           // elems per B slot
    const int t = threadIdx.x;
    const int l = t & 63, w = t >> 6;
    const int lr = l & 15, lhi = l >> 4;
    const int wm = w >> 2, wn = w & 3;
    const int orig = blockIdx.y * gridDim.x + blockIdx.x;   // nwg == 256
    const int sid = (orig & 7) * 32 + (orig >> 3);
    const int bm = sid & 31, bn = sid >> 5;

    const u16* Ag = A + (size_t)bm * 128 * K;
    const u16* Bg = B + (size_t)bn * BNT * K;

    auto STAGE = [&](int kt, int slot) {
        u16* As = lds + slot * ASZ;
        u16* Bs = lds + 4 * ASZ + slot * BSZ;
        {
            int c = t, row = c >> 2, cp = c & 3;
            int gc = (cp ^ ((row >> 1) & 3)) << 3;
            gload_lds16(Ag + (size_t)row * K + kt * 32 + gc, As + c * 8);
        }
        #pragma unroll
        for (int i = 0; i < NCH - 1; ++i) {
            int c = i * 512 + t, row = c >> 2, cp = c & 3;
            int gc = (cp ^ ((row >> 1) & 3)) << 3;
            gload_lds16(Bg + (size_t)row * K + kt * 32 + gc, Bs + c * 8);
        }
    };

    f32x4 acc[4][NACC] = {};
    const int NT = K >> 5;          // 32
    STAGE(0, 0);
    STAGE(1, 1);
    STAGE(2, 2);

    const int ckey = (lr >> 1) & 3;  // read-side swizzle key

    for (int kt = 0; kt < NT; ++kt) {
        if (kt < NT - 2) {
            if constexpr (NCH == 4) asm volatile("s_waitcnt vmcnt(8)" ::: "memory");
            else                    asm volatile("s_waitcnt vmcnt(4)" ::: "memory");
        } else if (kt == NT - 2) {
            if constexpr (NCH == 4) asm volatile("s_waitcnt vmcnt(4)" ::: "memory");
            else                    asm volatile("s_waitcnt vmcnt(2)" ::: "memory");
        } else {
            asm volatile("s_waitcnt vmcnt(0)" ::: "memory");
        }
        __builtin_amdgcn_s_barrier();

        if (kt + 3 < NT) STAGE(kt + 3, (kt + 3) & 3);

        const u16* As = lds + (kt & 3) * ASZ;
        const u16* Bs = lds + 4 * ASZ + (kt & 3) * BSZ;
        bf16x8 af[4], bfv[NACC];
        #pragma unroll
        for (int m = 0; m < 4; ++m) {
            int row = wm * 64 + m * 16 + lr;
            af[m] = *(const bf16x8*)(As + row * 32 + ((lhi ^ ckey) << 3));
        }
        #pragma unroll
        for (int n = 0; n < NACC; ++n) {
            int row = wn * (BNT / 4) + n * 16 + lr;
            bfv[n] = *(const bf16x8*)(Bs + row * 32 + ((lhi ^ ckey) << 3));
        }
        asm volatile("s_waitcnt lgkmcnt(0)" ::: "memory");
        __builtin_amdgcn_sched_barrier(0);
        __builtin_amdgcn_s_setprio(1);
        #pragma unroll
        for (int m = 0; m < 4; ++m)
            #pragma unroll
            for (int n = 0; n < NACC; ++n)
                acc[m][n] = __builtin_amdgcn_mfma_f32_16x16x32_bf16(
                    af[m], bfv[n], acc[m][n], 0, 0, 0);
        __builtin_amdgcn_s_setprio(0);
    }

    const int row0 = bm * 128 + wm * 64 + lhi * 4;
    const int col0 = bn * BNT + wn * (BNT / 4) + lr;
    #pragma unroll
    for (int n = 0; n < NACC; ++n) {
        int col = col0 + n * 16;
        float bv = bias[col];
        if (col < qcols) bv *= qscale;
        #pragma unroll
        for (int m = 0; m < 4; ++m)
            #pragma unroll
            for (int r = 0; r < 4; ++r) {
                int row = row0 + m * 16 + r;
                float v = acc[m][n][r] + bv;
                if constexpr (BF16_OUT)
                    ((u16*)Cv)[(size_t)row * N + col] = f32_to_bf16(v);
                else
                    ((float*)Cv)[(size_t)row * N + col] = v;
            }
    }
}

// V-transpose write: thread owns rows (2g, 2g+1), cols cl*8..cl*8+7.
__device__ __forceinline__ void write_vt(u16* vt, uint4 a, uint4 b, int g, int cl) {
    unsigned aw[4] = {a.x, a.y, a.z, a.w};
    unsigned bw[4] = {b.x, b.y, b.z, b.w};
    #pragma unroll
    for (int j = 0; j < 8; ++j) {
        int dh = cl * 8 + j;
        unsigned sel = (j & 1) ? 0x07060302u : 0x05040100u;
        unsigned v = __builtin_amdgcn_perm(bw[j >> 1], aw[j >> 1], sel);
        *(unsigned*)(vt + swzv(dh, g >> 2) + (2 * g & 7)) = v;
    }
}

// ---------------- causal flash attention: dual-parity 8-wave blocks --------
// Dynamic LDS 80 KB: Ks[2][2][4096] | Vt[2][2][4096] | Ps[8][1024].
// Counted-vmcnt pipeline: all prefetch issued UNCONDITIONALLY (tail over-reads
// stay inside d_ws), V regs carry a 2-iteration lead, one raw s_barrier/iter
// preceded by s_waitcnt vmcnt(2) (only V(t+4) stays in flight).
// Hazards: RAW Ks[cur]: every wave waited its own K(t+2) loads (vmcnt(2))
//   before the barrier ending iter i -> tile complete when read at iter i+1.
//   WAR: all LDS reads are lgkm-retired before each wave's last MFMA of the
//   iter, hence before the barrier; (re)writes are issued after that barrier.
__global__ __launch_bounds__(512, 4) void attn_kernel(const u16* __restrict__ qkv,
                                                      u16* __restrict__ out) {
    extern __shared__ u16 alds[];
    const int t = threadIdx.x;
    const int w = t >> 6, l = t & 63;
    const int lr = l & 15, lhi = l >> 4;
    const int par = w >> 2, wl = w & 3;
    const int tp = t & 255;            // index within parity's 4 waves
    const int orig = blockIdx.x;
    const int sid = (orig & 7) * 64 + (orig >> 3);   // XCD-chunked
    const int bh = sid >> 4, bi = sid & 15;
    const int h = bh & 15, b = bh >> 4;

    const u16* Kg = qkv + ((size_t)(b * 2048)) * 3072 + 1024 + h * 64;
    const u16* Vg = qkv + ((size_t)(b * 2048)) * 3072 + 2048 + h * 64;
    const int vg = tp >> 3, vcl = tp & 7;
    u16* KsP = alds + par * 8192;           // [2][4096] dbuf
    u16* VtP = alds + 16384 + par * 8192;   // [2][4096] dbuf
    u16* Pw = alds + 32768 + w * 1024;
    unsigned* Pst = (unsigned*)Pw;
    float2* mlX = (float2*)alds;            // aliases Ks[0][0]; epilogue-only

    #pragma unroll 1
    for (int pass = 0; pass < 2; ++pass) {
        const int qt = pass ? (31 - bi) : bi;
        __syncthreads();  // pass boundary: previous pass's LDS fully consumed

        const u16* Qrow = qkv + ((size_t)(b * 2048 + qt * 64 + wl * 16 + lr)) * 3072 + h * 64;
        bf16x8 qf0 = *(const bf16x8*)(Qrow + lhi * 8);
        bf16x8 qf1 = *(const bf16x8*)(Qrow + 32 + lhi * 8);

        // prologue: K(par) async -> Ks[0]; V(par) -> Vt[0]; V(par+2) -> regs
        #pragma unroll
        for (int i = 0; i < 2; ++i) {
            int c = i * 256 + tp, r = c >> 3, cl = c & 7;
            gload_lds16(Kg + ((size_t)(par * 64 + r)) * 3072 + ((cl ^ (r & 7)) << 3),
                        KsP + c * 8);
        }
        uint4 va0 = *(const uint4*)(Vg + ((size_t)(par * 64 + 2 * vg)) * 3072 + vcl * 8);
        uint4 vb0 = *(const uint4*)(Vg + ((size_t)(par * 64 + 2 * vg + 1)) * 3072 + vcl * 8);
        uint4 vaC = *(const uint4*)(Vg + ((size_t)((par + 2) * 64 + 2 * vg)) * 3072 + vcl * 8);
        uint4 vbC = *(const uint4*)(Vg + ((size_t)((par + 2) * 64 + 2 * vg + 1)) * 3072 + vcl * 8);
        write_vt(VtP, va0, vb0, vg, vcl);
        __syncthreads();

        f32x4 acc[4] = {};
        float m_run = -1e30f, l_run = 0.f;  // per-lane, q-row = lr; l deferred
        int cur = 0;
        const int nt = (qt >> 1) + 1;

        for (int it = 0; it < nt; ++it) {
            const int t64 = 2 * it + par;
            const bool active = (t64 <= qt);

            // --- unconditional prefetch issue (K: t+2 -> LDS, V: t+4 -> regs)
            #pragma unroll
            for (int i = 0; i < 2; ++i) {
                int c = i * 256 + tp, r = c >> 3, cl = c & 7;
                gload_lds16(Kg + ((size_t)((t64 + 2) * 64 + r)) * 3072 +
                                ((cl ^ (r & 7)) << 3),
                            KsP + (cur ^ 1) * 4096 + c * 8);
            }
            uint4 vaN = *(const uint4*)(Vg + ((size_t)((t64 + 4) * 64 + 2 * vg)) * 3072 + vcl * 8);
            uint4 vbN = *(const uint4*)(Vg + ((size_t)((t64 + 4) * 64 + 2 * vg + 1)) * 3072 + vcl * 8);

            if (active) {
                // S^T = K Q^T: sv[n] rows kv = n*16+lhi*4+r, col q = lr
                const u16* Kc = KsP + cur * 4096;
                __builtin_amdgcn_s_setprio(1);
                f32x4 sv[4] = {};
                #pragma unroll
                for (int kks = 0; kks < 2; ++kks) {
                    #pragma unroll
                    for (int n = 0; n < 4; ++n) {
                        bf16x8 kf = *(const bf16x8*)(Kc + swz(n * 16 + lr, kks * 4 + lhi));
                        sv[n] = __builtin_amdgcn_mfma_f32_16x16x32_bf16(
                            kf, kks ? qf1 : qf0, sv[n], 0, 0, 0);
                    }
                }
                __builtin_amdgcn_s_setprio(0);

                if (t64 == qt) {  // causal mask (diag tile only)
                    #pragma unroll
                    for (int n = 0; n < 4; ++n)
                        #pragma unroll
                        for (int r = 0; r < 4; ++r)
                            if ((n * 16 + lhi * 4 + r) > (wl * 16 + lr)) sv[n][r] = -1e30f;
                }
                float t0 = fmaxf(fmaxf(sv[0][0], sv[0][1]), fmaxf(sv[0][2], sv[0][3]));
                float t1 = fmaxf(fmaxf(sv[1][0], sv[1][1]), fmaxf(sv[1][2], sv[1][3]));
                float t2 = fmaxf(fmaxf(sv[2][0], sv[2][1]), fmaxf(sv[2][2], sv[2][3]));
                float t3 = fmaxf(fmaxf(sv[3][0], sv[3][1]), fmaxf(sv[3][2], sv[3][3]));
                float mx = fmaxf(fmaxf(t0, t1), fmaxf(t2, t3));
                mx = fmaxf(mx, __shfl_xor(mx, 16, 64));
                mx = fmaxf(mx, __shfl_xor(mx, 32, 64));

                if (__any(mx > m_run + 8.f)) {  // defer-max (THR=8, exp2 domain)
                    float mn = fmaxf(m_run, mx);
                    float alpha = exp2f(m_run - mn);
                    m_run = mn;
                    l_run *= alpha;
                    #pragma unroll
                    for (int r = 0; r < 4; ++r) {
                        float ar = __shfl(alpha, lhi * 4 + r, 16);
                        #pragma unroll
                        for (int n = 0; n < 4; ++n) acc[n][r] *= ar;
                    }
                }

                float rs = 0.f;
                #pragma unroll
                for (int n = 0; n < 4; ++n)
                    #pragma unroll
                    for (int r = 0; r < 4; ++r) {
                        float pe = exp2f(sv[n][r] - m_run);
                        sv[n][r] = pe;
                        rs += pe;
                    }
                l_run += rs;

                // pack kv-pairs -> u32, store to wave-private A-frag scratch
                #pragma unroll
                for (int n = 0; n < 4; ++n)
                    #pragma unroll
                    for (int rp = 0; rp < 2; ++rp) {
                        union { unsigned u; __bf16 hh[2]; } pk;
                        pk.hh[0] = (__bf16)sv[n][2 * rp];
                        pk.hh[1] = (__bf16)sv[n][2 * rp + 1];
                        int pp = 8 * n + 2 * lhi + rp;
                        Pst[lr * 32 + (((pp >> 2) ^ (lr & 7)) << 2) + (pp & 3)] = pk.u;
                    }
            }

            // V(t+2) regs (1-iter old) -> other Vt buffer; rotate the V lead
            write_vt(VtP + (cur ^ 1) * 4096, vaC, vbC, vg, vcl);
            vaC = vaN; vbC = vbN;

            if (active) {
                // O += P V  (wave-private P; Vt[cur])
                const u16* Vc = VtP + cur * 4096;
                __builtin_amdgcn_s_setprio(1);
                #pragma unroll
                for (int kks = 0; kks < 2; ++kks) {
                    bf16x8 pa = *(const bf16x8*)(Pw + lr * 64 +
                                                 (((kks * 4 + lhi) ^ (lr & 7)) << 3));
                    #pragma unroll
                    for (int n = 0; n < 4; ++n) {
                        bf16x8 vb = *(const bf16x8*)(Vc + swzv(n * 16 + lr, kks * 4 + lhi));
                        acc[n] = __builtin_amdgcn_mfma_f32_16x16x32_bf16(pa, vb, acc[n], 0, 0, 0);
                    }
                }
                __builtin_amdgcn_s_setprio(0);
            }

            // counted wait: K(t+2) retired (only V(t+4) left in flight), no drain
            asm volatile("s_waitcnt vmcnt(2)" ::: "memory");
            __builtin_amdgcn_s_barrier();
            cur ^= 1;
        }

        // deferred l reduction across the 4 lhi groups
        l_run += __shfl_xor(l_run, 16, 64);
        l_run += __shfl_xor(l_run, 32, 64);

        // parity exchange: par1 publishes (m,l) + unnormalized O; par0 combines
        if (par == 1) {
            if (lhi == 0) mlX[wl * 16 + lr] = make_float2(m_run, l_run);
            #pragma unroll
            for (int r = 0; r < 4; ++r)
                #pragma unroll
                for (int n = 0; n < 4; ++n)
                    Pw[(lhi * 4 + r) * 64 + n * 16 + lr] = f32_to_bf16(acc[n][r]);
        }
        __syncthreads();
        if (par == 0) {
            float2 m1l1 = mlX[wl * 16 + lr];
            float m = fmaxf(m_run, m1l1.x);
            float e0 = exp2f(m_run - m), e1 = exp2f(m1l1.x - m);
            float inv = 1.0f / (l_run * e0 + m1l1.y * e1);
            float c0 = e0 * inv, c1 = e1 * inv;
            const u16* Pq = alds + 32768 + (4 + wl) * 1024;
            #pragma unroll
            for (int r = 0; r < 4; ++r) {
                float c0r = __shfl(c0, lhi * 4 + r, 16);
                float c1r = __shfl(c1, lhi * 4 + r, 16);
                int qg = qt * 64 + wl * 16 + lhi * 4 + r;
                size_t base = ((size_t)(b * 2048 + qg)) * 1024 + h * 64;
                #pragma unroll
                for (int n = 0; n < 4; ++n) {
                    float v1 = bf16_f(Pq[(lhi * 4 + r) * 64 + n * 16 + lr]);
                    out[base + n * 16 + lr] = f32_to_bf16(acc[n][r] * c0r + v1 * c1r);
                }
            }
        }
    }
}

extern "C" void kernel_launch(void* const* d_in, const int* in_sizes, int n_in,
                              void* d_out, int out_size, void* d_ws, size_t ws_size,
                              hipStream_t stream) {
    const float* x = (const float*)d_in[0];
    const float* w_in = (const float*)d_in[1];
    const float* b_in = (const float*)d_in[2];
    const float* w_out = (const float*)d_in[3];
    const float* b_out = (const float*)d_in[4];
    float* out = (float*)d_out;

    // workspace layout (bf16), 48 MB
    u16* xb = (u16*)d_ws;                            // [4096][1024]
    u16* wib = xb + (size_t)4096 * 1024;             // [3072][1024]
    u16* wob = wib + (size_t)3072 * 1024;            // [1024][1024]
    u16* qkvb = wob + (size_t)1024 * 1024;           // [4096][3072]
    u16* attnb = qkvb + (size_t)4096 * 3072;         // [4096][1024]

    const int n0 = 4096 * 1024 / 4, n1 = 3072 * 1024 / 4, n2 = 1024 * 1024 / 4;
    cvt_bf16_3<<<2048, 256, 0, stream>>>((const float4*)x, (const float4*)w_in,
                                         (const float4*)w_out, (uint2*)xb,
                                         n0, n1, n0 + n1 + n2);

    (void)hipFuncSetAttribute((const void*)gemm_ring<384, true>,
                              hipFuncAttributeMaxDynamicSharedMemorySize, 131072);
    (void)hipFuncSetAttribute((const void*)gemm_ring<128, false>,
                              hipFuncAttributeMaxDynamicSharedMemorySize, 65536);
    (void)hipFuncSetAttribute((const void*)attn_kernel,
                              hipFuncAttributeMaxDynamicSharedMemorySize, 81920);

    // qkv = x @ w_in^T + b_in (q-part pre-scaled) -> bf16 [4096][3072]
    gemm_ring<384, true><<<dim3(32, 8), 512, 131072, stream>>>(
        xb, wib, b_in, qkvb, 4096, 3072, 1024, 1024, QK_SCALE);
    // causal flash attention (dual-parity blocks, counted-vmcnt pipeline)
    attn_kernel<<<512, 512, 81920, stream>>>(qkvb, attnb);
    // out = attn @ w_out^T + b_out -> f32
    gemm_ring<128, false><<<dim3(32, 8), 512, 65536, stream>>>(
        attnb, wob, b_out, out, 4096, 1024, 1024, 0, 1.0f);
}